// Round 8
// baseline (233.538 us; speedup 1.0000x reference)
//
#include <hip/hip_runtime.h>
#include <math.h>

// LinearAttention: B=16, C=256, H=W=64 (N=4096), 8 heads x 32 dim.
// R1: k_fold -> block-per-(b,h) LDS kernel.
// R2: k_ctxpart -> MFMA fragments straight from global.
// R3: xnbT pre-transpose (rinv folded); GEMM staging pure uint4.
// R6: k_qfinal fuses q-GEMM + softmax + M@q + epilogue.
// R7: (reverted for k_gemm) stage-B-once experiment: k_qfinal unchanged
//     perf -> NOT barrier-bound; k_gemm regressed (2 blk/CU).
// R8: k_qfinal is latency/occupancy-bound (occ 36%, all pipes idle):
//     overlay q-LDS onto xn-LDS (67->35KB, 2->4 blocks/CU, launch_bounds
//     (512,8)); k_gemm reverted to R6 barriered 128x128 (20KB LDS).

#define B_ 16
#define C_ 256
#define N_ 4096
#define SCALE_ 0.17677669529663687f
#define EPS_ 1e-12f

typedef __attribute__((ext_vector_type(8))) short bf16x8;
typedef __attribute__((ext_vector_type(4))) float f32x4;

__device__ __forceinline__ ushort f2bf(float f) {
    union { float f; uint u; } x; x.f = f;
    uint r = (x.u + 0x7FFFu + ((x.u >> 16) & 1u)) >> 16;
    return (ushort)r;
}
__device__ __forceinline__ float bf2f(ushort s) {
    union { uint u; float f; } x; x.u = ((uint)s) << 16;
    return x.f;
}

// ---------------- K1: W' = w_qkv * g1 -> bf16 ----------------
__global__ __launch_bounds__(256) void k_prep(const float* __restrict__ w_qkv,
                                              const float* __restrict__ g1,
                                              ushort* __restrict__ Wp) {
    int o = blockIdx.x, c = threadIdx.x;
    Wp[(size_t)o * 256 + c] = f2bf(w_qkv[(size_t)o * 256 + c] * g1[c]);
}

// ---------------- K2: xnbT[b][n][c] = bf16(x[b][c][n] * rinv[b][n]) -------
__global__ __launch_bounds__(256) void k_xconv(const float* __restrict__ x,
                                               ushort* __restrict__ xnbT) {
    __shared__ float ssp[4][64];
    __shared__ float rinv_s[64];
    __shared__ ushort T[64][268];
    int b = blockIdx.y, n0 = blockIdx.x * 64;
    const float* xb = x + (size_t)b * C_ * N_ + n0;
    int t = threadIdx.x;
    int nl = t & 63, cg = t >> 6;
    float ss = 0.f;
    #pragma unroll 8
    for (int i = 0; i < 64; ++i) {
        float v = xb[(size_t)(cg * 64 + i) * N_ + nl];
        ss += v * v;
    }
    ssp[cg][nl] = ss;
    __syncthreads();
    if (t < 64)
        rinv_s[t] = 16.f / fmaxf(sqrtf(ssp[0][t] + ssp[1][t] + ssp[2][t] + ssp[3][t]), EPS_);
    __syncthreads();
    float rv = rinv_s[nl];
    #pragma unroll 8
    for (int i = 0; i < 64; ++i) {
        int c = cg * 64 + i;
        T[nl][c] = f2bf(xb[(size_t)c * N_ + nl] * rv);   // L2-hot re-read
    }
    __syncthreads();
    int j = t >> 2, ch = t & 3;
    ushort* orow = xnbT + ((size_t)b * N_ + n0 + j) * 256 + ch * 64;
    #pragma unroll
    for (int i = 0; i < 8; ++i)
        *(uint2*)&orow[i * 8] = *(const uint2*)&T[j][ch * 64 + i * 8],
        *(uint2*)&orow[i * 8 + 4] = *(const uint2*)&T[j][ch * 64 + i * 8 + 4];
}

// ---------------- K3: kv GEMM  kv = Wp[256..767] @ xn ----------------
// R6 version: tile 128x128, BK=32, 4 waves each 64x64 via 16x16x32 MFMA.
__global__ __launch_bounds__(256) void k_gemm(const ushort* __restrict__ Wp,
                                              const ushort* __restrict__ xnbT,
                                              ushort* __restrict__ kvOut) {
    __shared__ ushort Asub[128][40];
    __shared__ ushort Bsub[128][40];
    const int b = blockIdx.z;
    const int wrow0 = 256 + blockIdx.y * 128;
    const int col0 = blockIdx.x * 128;
    const int t = threadIdx.x;
    const int l = t & 63, w = t >> 6;
    const int wr = w >> 1, wc = w & 1, grp = l >> 4;
    const ushort* xb = xnbT + (size_t)b * N_ * 256;
    f32x4 acc[4][4] = {};

    for (int k0 = 0; k0 < 256; k0 += 32) {
        int r = t >> 1, ko = (t & 1) * 16;
        const uint4* sa = (const uint4*)(Wp + (size_t)(wrow0 + r) * 256 + k0 + ko);
        *(uint4*)&Asub[r][ko]     = sa[0];
        *(uint4*)&Asub[r][ko + 8] = sa[1];
        const uint4* sb = (const uint4*)(xb + (size_t)(col0 + r) * 256 + k0 + ko);
        *(uint4*)&Bsub[r][ko]     = sb[0];
        *(uint4*)&Bsub[r][ko + 8] = sb[1];
        __syncthreads();
        bf16x8 af[4], bfv[4];
        #pragma unroll
        for (int m = 0; m < 4; ++m)
            af[m] = *(const bf16x8*)&Asub[wr * 64 + m * 16 + (l & 15)][grp * 8];
        #pragma unroll
        for (int n = 0; n < 4; ++n)
            bfv[n] = *(const bf16x8*)&Bsub[wc * 64 + n * 16 + (l & 15)][grp * 8];
        #pragma unroll
        for (int m = 0; m < 4; ++m)
            #pragma unroll
            for (int n = 0; n < 4; ++n)
                acc[m][n] = __builtin_amdgcn_mfma_f32_16x16x32_bf16(af[m], bfv[n], acc[m][n], 0, 0, 0);
        __syncthreads();
    }

    ushort* kvb = kvOut + (size_t)b * 512 * N_;
    #pragma unroll
    for (int n = 0; n < 4; ++n) {
        int cg = col0 + wc * 64 + n * 16 + (l & 15);
        #pragma unroll
        for (int m = 0; m < 4; ++m) {
            int rbase = wrow0 - 256 + wr * 64 + m * 16 + grp * 4;
            #pragma unroll
            for (int r = 0; r < 4; ++r)
                kvb[(size_t)(rbase + r) * N_ + cg] = f2bf(acc[m][n][r]);
        }
    }
}

// ---------------- K4: partial ctx = P @ V^T via MFMA, psum = P @ 1 --------
__global__ __launch_bounds__(256) void k_ctxpart(const ushort* __restrict__ kv,
                                                 float* __restrict__ ctxp,
                                                 float* __restrict__ sums_p) {
    __shared__ float red[4][32][33];
    __shared__ float redp[4][32];
    int bh = blockIdx.x, s = blockIdx.y;
    int b = bh >> 3, h = bh & 7;
    int t = threadIdx.x, l = t & 63, w = t >> 6;
    const ushort* kb = kv + (size_t)b * 512 * N_ + (size_t)(h * 32) * N_;
    const ushort* vb = kv + (size_t)b * 512 * N_ + (size_t)(256 + h * 32) * N_;
    const int n0base = s * 1024 + w * 256;
    const int row = l & 15, grp = l >> 4;
    f32x4 acc[2][2] = {};
    float psA = 0.f, psB = 0.f;

    for (int it = 0; it < 8; ++it) {
        int n0 = n0base + it * 32 + grp * 8;
        bf16x8 k0 = *(const bf16x8*)&kb[(size_t)row * N_ + n0];
        bf16x8 k1 = *(const bf16x8*)&kb[(size_t)(row + 16) * N_ + n0];
        bf16x8 v0 = *(const bf16x8*)&vb[(size_t)row * N_ + n0];
        bf16x8 v1 = *(const bf16x8*)&vb[(size_t)(row + 16) * N_ + n0];
        bf16x8 p0, p1;
        #pragma unroll
        for (int j = 0; j < 8; ++j) {
            ushort r0 = f2bf(__expf(bf2f((ushort)k0[j])));
            ushort r1 = f2bf(__expf(bf2f((ushort)k1[j])));
            p0[j] = (short)r0; p1[j] = (short)r1;
            psA += bf2f(r0); psB += bf2f(r1);
        }
        acc[0][0] = __builtin_amdgcn_mfma_f32_16x16x32_bf16(p0, v0, acc[0][0], 0, 0, 0);
        acc[0][1] = __builtin_amdgcn_mfma_f32_16x16x32_bf16(p0, v1, acc[0][1], 0, 0, 0);
        acc[1][0] = __builtin_amdgcn_mfma_f32_16x16x32_bf16(p1, v0, acc[1][0], 0, 0, 0);
        acc[1][1] = __builtin_amdgcn_mfma_f32_16x16x32_bf16(p1, v1, acc[1][1], 0, 0, 0);
    }

    psA += __shfl_xor(psA, 16); psA += __shfl_xor(psA, 32);
    psB += __shfl_xor(psB, 16); psB += __shfl_xor(psB, 32);
    #pragma unroll
    for (int mi = 0; mi < 2; ++mi)
        #pragma unroll
        for (int ni = 0; ni < 2; ++ni)
            #pragma unroll
            for (int r = 0; r < 4; ++r)
                red[w][mi * 16 + grp * 4 + r][ni * 16 + row] = acc[mi][ni][r];
    if (l < 16) { redp[w][l] = psA; redp[w][16 + l] = psB; }
    __syncthreads();

    size_t base = (size_t)(s * 128 + bh) * 32;
    #pragma unroll
    for (int i = t; i < 1024; i += 256) {
        int d = i >> 5, e = i & 31;
        ctxp[(base + d) * 32 + e] =
            red[0][d][e] + red[1][d][e] + red[2][d][e] + red[3][d][e];
    }
    if (t < 32)
        sums_p[base + t] = redp[0][t] + redp[1][t] + redp[2][t] + redp[3][t];
}

// ---------------- K5: M[b][o][h*32+d] = SCALE/stot[d] * sum_e w_out.ctx ----
__global__ __launch_bounds__(256) void k_fold(const float* __restrict__ w_out,
                                              const float* __restrict__ ctxp,
                                              const float* __restrict__ sums_p,
                                              ushort* __restrict__ M) {
    __shared__ float cn[32][33];
    __shared__ float sinv[32];
    int bh = blockIdx.x;
    int b = bh >> 3, h = bh & 7;
    int t = threadIdx.x;
    if (t < 32) {
        float st = 0.f;
        #pragma unroll
        for (int s = 0; s < 4; ++s) st += sums_p[(size_t)(s * 128 + bh) * 32 + t];
        sinv[t] = SCALE_ / st;
    }
    #pragma unroll
    for (int i = t; i < 1024; i += 256) {
        int d = i >> 5, e = i & 31;
        float cv = 0.f;
        #pragma unroll
        for (int s = 0; s < 4; ++s)
            cv += ctxp[((size_t)(s * 128 + bh) * 32 + d) * 32 + e];
        cn[e][d] = cv;
    }
    __syncthreads();
    float wreg[32];
    const float* wr = w_out + (size_t)t * 256 + h * 32;
    #pragma unroll
    for (int e = 0; e < 32; e += 4) {
        float4 wv = *(const float4*)&wr[e];
        wreg[e] = wv.x; wreg[e + 1] = wv.y; wreg[e + 2] = wv.z; wreg[e + 3] = wv.w;
    }
    float acc[32] = {};
    #pragma unroll
    for (int e = 0; e < 32; ++e) {
        float we = wreg[e];
        #pragma unroll
        for (int d = 0; d < 32; ++d) acc[d] += we * cn[e][d];
    }
    ushort* Mrow = M + ((size_t)b * 256 + t) * 256 + h * 32;
    #pragma unroll
    for (int d = 0; d < 32; ++d) Mrow[d] = f2bf(acc[d] * sinv[d]);
}

// ---------------- K6: fused q-GEMM + softmax + M@q + epilogue ----------
// grid (64 coltiles, 16 b), 512 threads = 8 waves; wave = head = 32 rows.
// ONE 32KB LDS buffer: xn B-tile staged once (swizzled), consumed by GEMM1,
// then overlaid with softmaxed q (barrier-fenced), consumed by GEMM2.
// A-frags (Wq then M) from L2-hot global in-loop; latency hidden by
// 4 blocks/CU (32 waves/CU).
__global__ __launch_bounds__(512, 8) void k_qfinal(const ushort* __restrict__ Wp,
                                                   const ushort* __restrict__ xnbT,
                                                   const ushort* __restrict__ M,
                                                   const float* __restrict__ b_out,
                                                   const float* __restrict__ g2,
                                                   const float* __restrict__ x,
                                                   float* __restrict__ out) {
    __shared__ ushort BQ[64 * 256];   // swizzled: byte = (row*512+k*2) ^ ((row&7)<<4)
    __shared__ float ss2[8][64];
    const int b = blockIdx.y, col0 = blockIdx.x * 64;
    const int t = threadIdx.x, l = t & 63, w = t >> 6;
    const int lr = l & 15, grp = l >> 4;
    const ushort* xb = xnbT + (size_t)b * N_ * 256;

    {   // stage xn B-tile: 8 threads/row, 64B each
        int row = t >> 3, seg = t & 7;
        const uint4* src = (const uint4*)(xb + (size_t)(col0 + row) * 256 + seg * 32);
        uint base = (uint)(row * 512 + seg * 64);
        uint sw = (uint)((row & 7) << 4);
        #pragma unroll
        for (int i = 0; i < 4; ++i)
            *(uint4*)((char*)BQ + ((base + i * 16) ^ sw)) = src[i];
    }
    __syncthreads();

    // ---- GEMM1: q = Wq @ xn (wave w -> rows w*32..w*32+31) ----
    f32x4 acc[2][4] = {};
    for (int k0 = 0; k0 < 256; k0 += 32) {
        bf16x8 af[2], bf[4];
        #pragma unroll
        for (int m = 0; m < 2; ++m)
            af[m] = *(const bf16x8*)(Wp + (size_t)(w * 32 + m * 16 + lr) * 256 + k0 + grp * 8);
        #pragma unroll
        for (int n = 0; n < 4; ++n) {
            int row = n * 16 + lr;
            uint off = (uint)(row * 512 + (k0 + grp * 8) * 2) ^ (uint)((row & 7) << 4);
            bf[n] = *(const bf16x8*)((const char*)BQ + off);
        }
        #pragma unroll
        for (int m = 0; m < 2; ++m)
            #pragma unroll
            for (int n = 0; n < 4; ++n)
                acc[m][n] = __builtin_amdgcn_mfma_f32_16x16x32_bf16(af[m], bf[n], acc[m][n], 0, 0, 0);
    }
    __syncthreads();   // all GEMM1 reads of BQ (xn) complete

    // ---- per-head softmax over d (wave = head), overlay q into BQ ----
    #pragma unroll
    for (int n = 0; n < 4; ++n) {
        float f[2][4];
        #pragma unroll
        for (int m = 0; m < 2; ++m)
            #pragma unroll
            for (int r = 0; r < 4; ++r) f[m][r] = acc[m][n][r];
        float mx = -1e30f;
        #pragma unroll
        for (int r = 0; r < 4; ++r) mx = fmaxf(mx, fmaxf(f[0][r], f[1][r]));
        mx = fmaxf(mx, __shfl_xor(mx, 16));
        mx = fmaxf(mx, __shfl_xor(mx, 32));
        float s = 0.f;
        #pragma unroll
        for (int r = 0; r < 4; ++r) {
            f[0][r] = __expf(f[0][r] - mx); s += f[0][r];
            f[1][r] = __expf(f[1][r] - mx); s += f[1][r];
        }
        s += __shfl_xor(s, 16); s += __shfl_xor(s, 32);
        float inv = 1.f / s;
        int cl = n * 16 + lr;
        #pragma unroll
        for (int m = 0; m < 2; ++m) {
            int d = w * 32 + m * 16 + grp * 4;
            uint2 pk;
            pk.x = (uint)f2bf(f[m][0] * inv) | ((uint)f2bf(f[m][1] * inv) << 16);
            pk.y = (uint)f2bf(f[m][2] * inv) | ((uint)f2bf(f[m][3] * inv) << 16);
            uint off = (uint)(cl * 512 + d * 2) ^ (uint)((cl & 7) << 4);
            *(uint2*)((char*)BQ + off) = pk;
        }
    }
    __syncthreads();   // all waves' q visible

    // ---- GEMM2: out = M @ q ----
    f32x4 acc2[2][4] = {};
    const ushort* Mb = M + (size_t)b * 256 * 256;
    for (int k0 = 0; k0 < 256; k0 += 32) {
        bf16x8 af[2], bq[4];
        #pragma unroll
        for (int m = 0; m < 2; ++m)
            af[m] = *(const bf16x8*)(Mb + (size_t)(w * 32 + m * 16 + lr) * 256 + k0 + grp * 8);
        #pragma unroll
        for (int n = 0; n < 4; ++n) {
            int row = n * 16 + lr;
            uint off = (uint)(row * 512 + (k0 + grp * 8) * 2) ^ (uint)((row & 7) << 4);
            bq[n] = *(const bf16x8*)((const char*)BQ + off);
        }
        #pragma unroll
        for (int m = 0; m < 2; ++m)
            #pragma unroll
            for (int n = 0; n < 4; ++n)
                acc2[m][n] = __builtin_amdgcn_mfma_f32_16x16x32_bf16(af[m], bq[n], acc2[m][n], 0, 0, 0);
    }

    // ---- epilogue: +b_out, column sum-of-squares over 256 rows ----
    #pragma unroll
    for (int n = 0; n < 4; ++n) {
        float local = 0.f;
        #pragma unroll
        for (int m = 0; m < 2; ++m) {
            int obase = w * 32 + m * 16 + grp * 4;
            #pragma unroll
            for (int r = 0; r < 4; ++r) {
                float f = acc2[m][n][r] + b_out[obase + r];
                acc2[m][n][r] = f;
                local += f * f;
            }
        }
        local += __shfl_xor(local, 16);
        local += __shfl_xor(local, 32);
        if (grp == 0) ss2[w][n * 16 + lr] = local;
    }
    __syncthreads();
    const float* xb2 = x + (size_t)b * C_ * N_;
    float* ob = out + (size_t)b * C_ * N_;
    #pragma unroll
    for (int n = 0; n < 4; ++n) {
        int cl = n * 16 + lr;
        int cg = col0 + cl;
        float tot = ss2[0][cl] + ss2[1][cl] + ss2[2][cl] + ss2[3][cl]
                  + ss2[4][cl] + ss2[5][cl] + ss2[6][cl] + ss2[7][cl];
        float rs = 16.f / fmaxf(sqrtf(tot), EPS_);
        #pragma unroll
        for (int m = 0; m < 2; ++m) {
            int obase = w * 32 + m * 16 + grp * 4;
            #pragma unroll
            for (int r = 0; r < 4; ++r) {
                int o = obase + r;
                ob[(size_t)o * N_ + cg] = acc2[m][n][r] * rs * g2[o] + xb2[(size_t)o * N_ + cg];
            }
        }
    }
}

extern "C" void kernel_launch(void* const* d_in, const int* in_sizes, int n_in,
                              void* d_out, int out_size, void* d_ws, size_t ws_size,
                              hipStream_t stream) {
    const float* x     = (const float*)d_in[0];
    const float* g1    = (const float*)d_in[1];
    const float* w_qkv = (const float*)d_in[2];
    const float* w_out = (const float*)d_in[3];
    const float* b_out = (const float*)d_in[4];
    const float* g2    = (const float*)d_in[5];
    float* out = (float*)d_out;
    char* ws = (char*)d_ws;

    ushort* Wp     = (ushort*)(ws + 0);          //    393216 B
    float*  ctxp   = (float*)(ws + 393216);      //   2097152 B
    float*  sums_p = (float*)(ws + 2490368);     //     65536 B
    ushort* Mm     = (ushort*)(ws + 2555904);    //   2097152 B
    ushort* xnbT   = (ushort*)(ws + 4653056);    //  33554432 B
    ushort* kv     = (ushort*)(ws + 38207488);   //  67108864 B (total 100.4 MB)

    k_prep<<<768, 256, 0, stream>>>(w_qkv, g1, Wp);
    k_xconv<<<dim3(64, 16), 256, 0, stream>>>(x, xnbT);
    k_gemm<<<dim3(32, 4, 16), 256, 0, stream>>>(Wp, xnbT, kv);
    k_ctxpart<<<dim3(128, 4), 256, 0, stream>>>(kv, ctxp, sums_p);
    k_fold<<<128, 256, 0, stream>>>(w_out, ctxp, sums_p, Mm);
    k_qfinal<<<dim3(64, 16), 512, 0, stream>>>(Wp, xnbT, Mm, b_out, g2, x, out);
}

// Round 9
// 155.275 us; speedup vs baseline: 1.5040x; 1.5040x over previous
//
#include <hip/hip_runtime.h>
#include <math.h>

// LinearAttention: B=16, C=256, H=W=64 (N=4096), 8 heads x 32 dim.
// R1: k_fold -> block-per-(b,h) LDS kernel.
// R2: k_ctxpart -> MFMA fragments straight from global.
// R3: xnbT pre-transpose (rinv folded); GEMM staging pure uint4.
// R6: k_qfinal fuses q-GEMM + softmax + M@q + epilogue.
// R7: global-A experiment -> NOT barrier-bound; VGPR=60 proven.
// R8: LDS overlay (67->35KB) -> occ 77% PROVEN, but (512,8) reg-clamp
//     caused VGPR=32 + spills (FETCH 60->173MB, 58->148us).
// R9: keep overlay, drop the min-waves clamp: natural VGPR~60 (<=64)
//     + 35KB LDS = 4 blocks/CU without spills.

#define B_ 16
#define C_ 256
#define N_ 4096
#define SCALE_ 0.17677669529663687f
#define EPS_ 1e-12f

typedef __attribute__((ext_vector_type(8))) short bf16x8;
typedef __attribute__((ext_vector_type(4))) float f32x4;

__device__ __forceinline__ ushort f2bf(float f) {
    union { float f; uint u; } x; x.f = f;
    uint r = (x.u + 0x7FFFu + ((x.u >> 16) & 1u)) >> 16;
    return (ushort)r;
}
__device__ __forceinline__ float bf2f(ushort s) {
    union { uint u; float f; } x; x.u = ((uint)s) << 16;
    return x.f;
}

// ---------------- K1: W' = w_qkv * g1 -> bf16 ----------------
__global__ __launch_bounds__(256) void k_prep(const float* __restrict__ w_qkv,
                                              const float* __restrict__ g1,
                                              ushort* __restrict__ Wp) {
    int o = blockIdx.x, c = threadIdx.x;
    Wp[(size_t)o * 256 + c] = f2bf(w_qkv[(size_t)o * 256 + c] * g1[c]);
}

// ---------------- K2: xnbT[b][n][c] = bf16(x[b][c][n] * rinv[b][n]) -------
__global__ __launch_bounds__(256) void k_xconv(const float* __restrict__ x,
                                               ushort* __restrict__ xnbT) {
    __shared__ float ssp[4][64];
    __shared__ float rinv_s[64];
    __shared__ ushort T[64][268];
    int b = blockIdx.y, n0 = blockIdx.x * 64;
    const float* xb = x + (size_t)b * C_ * N_ + n0;
    int t = threadIdx.x;
    int nl = t & 63, cg = t >> 6;
    float ss = 0.f;
    #pragma unroll 8
    for (int i = 0; i < 64; ++i) {
        float v = xb[(size_t)(cg * 64 + i) * N_ + nl];
        ss += v * v;
    }
    ssp[cg][nl] = ss;
    __syncthreads();
    if (t < 64)
        rinv_s[t] = 16.f / fmaxf(sqrtf(ssp[0][t] + ssp[1][t] + ssp[2][t] + ssp[3][t]), EPS_);
    __syncthreads();
    float rv = rinv_s[nl];
    #pragma unroll 8
    for (int i = 0; i < 64; ++i) {
        int c = cg * 64 + i;
        T[nl][c] = f2bf(xb[(size_t)c * N_ + nl] * rv);   // L2-hot re-read
    }
    __syncthreads();
    int j = t >> 2, ch = t & 3;
    ushort* orow = xnbT + ((size_t)b * N_ + n0 + j) * 256 + ch * 64;
    #pragma unroll
    for (int i = 0; i < 8; ++i)
        *(uint2*)&orow[i * 8] = *(const uint2*)&T[j][ch * 64 + i * 8],
        *(uint2*)&orow[i * 8 + 4] = *(const uint2*)&T[j][ch * 64 + i * 8 + 4];
}

// ---------------- K3: kv GEMM  kv = Wp[256..767] @ xn ----------------
// tile 128x128, BK=32, 4 waves each 64x64 via 16x16x32 MFMA.
__global__ __launch_bounds__(256) void k_gemm(const ushort* __restrict__ Wp,
                                              const ushort* __restrict__ xnbT,
                                              ushort* __restrict__ kvOut) {
    __shared__ ushort Asub[128][40];
    __shared__ ushort Bsub[128][40];
    const int b = blockIdx.z;
    const int wrow0 = 256 + blockIdx.y * 128;
    const int col0 = blockIdx.x * 128;
    const int t = threadIdx.x;
    const int l = t & 63, w = t >> 6;
    const int wr = w >> 1, wc = w & 1, grp = l >> 4;
    const ushort* xb = xnbT + (size_t)b * N_ * 256;
    f32x4 acc[4][4] = {};

    for (int k0 = 0; k0 < 256; k0 += 32) {
        int r = t >> 1, ko = (t & 1) * 16;
        const uint4* sa = (const uint4*)(Wp + (size_t)(wrow0 + r) * 256 + k0 + ko);
        *(uint4*)&Asub[r][ko]     = sa[0];
        *(uint4*)&Asub[r][ko + 8] = sa[1];
        const uint4* sb = (const uint4*)(xb + (size_t)(col0 + r) * 256 + k0 + ko);
        *(uint4*)&Bsub[r][ko]     = sb[0];
        *(uint4*)&Bsub[r][ko + 8] = sb[1];
        __syncthreads();
        bf16x8 af[4], bfv[4];
        #pragma unroll
        for (int m = 0; m < 4; ++m)
            af[m] = *(const bf16x8*)&Asub[wr * 64 + m * 16 + (l & 15)][grp * 8];
        #pragma unroll
        for (int n = 0; n < 4; ++n)
            bfv[n] = *(const bf16x8*)&Bsub[wc * 64 + n * 16 + (l & 15)][grp * 8];
        #pragma unroll
        for (int m = 0; m < 4; ++m)
            #pragma unroll
            for (int n = 0; n < 4; ++n)
                acc[m][n] = __builtin_amdgcn_mfma_f32_16x16x32_bf16(af[m], bfv[n], acc[m][n], 0, 0, 0);
        __syncthreads();
    }

    ushort* kvb = kvOut + (size_t)b * 512 * N_;
    #pragma unroll
    for (int n = 0; n < 4; ++n) {
        int cg = col0 + wc * 64 + n * 16 + (l & 15);
        #pragma unroll
        for (int m = 0; m < 4; ++m) {
            int rbase = wrow0 - 256 + wr * 64 + m * 16 + grp * 4;
            #pragma unroll
            for (int r = 0; r < 4; ++r)
                kvb[(size_t)(rbase + r) * N_ + cg] = f2bf(acc[m][n][r]);
        }
    }
}

// ---------------- K4: partial ctx = P @ V^T via MFMA, psum = P @ 1 --------
__global__ __launch_bounds__(256) void k_ctxpart(const ushort* __restrict__ kv,
                                                 float* __restrict__ ctxp,
                                                 float* __restrict__ sums_p) {
    __shared__ float red[4][32][33];
    __shared__ float redp[4][32];
    int bh = blockIdx.x, s = blockIdx.y;
    int b = bh >> 3, h = bh & 7;
    int t = threadIdx.x, l = t & 63, w = t >> 6;
    const ushort* kb = kv + (size_t)b * 512 * N_ + (size_t)(h * 32) * N_;
    const ushort* vb = kv + (size_t)b * 512 * N_ + (size_t)(256 + h * 32) * N_;
    const int n0base = s * 1024 + w * 256;
    const int row = l & 15, grp = l >> 4;
    f32x4 acc[2][2] = {};
    float psA = 0.f, psB = 0.f;

    for (int it = 0; it < 8; ++it) {
        int n0 = n0base + it * 32 + grp * 8;
        bf16x8 k0 = *(const bf16x8*)&kb[(size_t)row * N_ + n0];
        bf16x8 k1 = *(const bf16x8*)&kb[(size_t)(row + 16) * N_ + n0];
        bf16x8 v0 = *(const bf16x8*)&vb[(size_t)row * N_ + n0];
        bf16x8 v1 = *(const bf16x8*)&vb[(size_t)(row + 16) * N_ + n0];
        bf16x8 p0, p1;
        #pragma unroll
        for (int j = 0; j < 8; ++j) {
            ushort r0 = f2bf(__expf(bf2f((ushort)k0[j])));
            ushort r1 = f2bf(__expf(bf2f((ushort)k1[j])));
            p0[j] = (short)r0; p1[j] = (short)r1;
            psA += bf2f(r0); psB += bf2f(r1);
        }
        acc[0][0] = __builtin_amdgcn_mfma_f32_16x16x32_bf16(p0, v0, acc[0][0], 0, 0, 0);
        acc[0][1] = __builtin_amdgcn_mfma_f32_16x16x32_bf16(p0, v1, acc[0][1], 0, 0, 0);
        acc[1][0] = __builtin_amdgcn_mfma_f32_16x16x32_bf16(p1, v0, acc[1][0], 0, 0, 0);
        acc[1][1] = __builtin_amdgcn_mfma_f32_16x16x32_bf16(p1, v1, acc[1][1], 0, 0, 0);
    }

    psA += __shfl_xor(psA, 16); psA += __shfl_xor(psA, 32);
    psB += __shfl_xor(psB, 16); psB += __shfl_xor(psB, 32);
    #pragma unroll
    for (int mi = 0; mi < 2; ++mi)
        #pragma unroll
        for (int ni = 0; ni < 2; ++ni)
            #pragma unroll
            for (int r = 0; r < 4; ++r)
                red[w][mi * 16 + grp * 4 + r][ni * 16 + row] = acc[mi][ni][r];
    if (l < 16) { redp[w][l] = psA; redp[w][16 + l] = psB; }
    __syncthreads();

    size_t base = (size_t)(s * 128 + bh) * 32;
    #pragma unroll
    for (int i = t; i < 1024; i += 256) {
        int d = i >> 5, e = i & 31;
        ctxp[(base + d) * 32 + e] =
            red[0][d][e] + red[1][d][e] + red[2][d][e] + red[3][d][e];
    }
    if (t < 32)
        sums_p[base + t] = redp[0][t] + redp[1][t] + redp[2][t] + redp[3][t];
}

// ---------------- K5: M[b][o][h*32+d] = SCALE/stot[d] * sum_e w_out.ctx ----
__global__ __launch_bounds__(256) void k_fold(const float* __restrict__ w_out,
                                              const float* __restrict__ ctxp,
                                              const float* __restrict__ sums_p,
                                              ushort* __restrict__ M) {
    __shared__ float cn[32][33];
    __shared__ float sinv[32];
    int bh = blockIdx.x;
    int b = bh >> 3, h = bh & 7;
    int t = threadIdx.x;
    if (t < 32) {
        float st = 0.f;
        #pragma unroll
        for (int s = 0; s < 4; ++s) st += sums_p[(size_t)(s * 128 + bh) * 32 + t];
        sinv[t] = SCALE_ / st;
    }
    #pragma unroll
    for (int i = t; i < 1024; i += 256) {
        int d = i >> 5, e = i & 31;
        float cv = 0.f;
        #pragma unroll
        for (int s = 0; s < 4; ++s)
            cv += ctxp[((size_t)(s * 128 + bh) * 32 + d) * 32 + e];
        cn[e][d] = cv;
    }
    __syncthreads();
    float wreg[32];
    const float* wr = w_out + (size_t)t * 256 + h * 32;
    #pragma unroll
    for (int e = 0; e < 32; e += 4) {
        float4 wv = *(const float4*)&wr[e];
        wreg[e] = wv.x; wreg[e + 1] = wv.y; wreg[e + 2] = wv.z; wreg[e + 3] = wv.w;
    }
    float acc[32] = {};
    #pragma unroll
    for (int e = 0; e < 32; ++e) {
        float we = wreg[e];
        #pragma unroll
        for (int d = 0; d < 32; ++d) acc[d] += we * cn[e][d];
    }
    ushort* Mrow = M + ((size_t)b * 256 + t) * 256 + h * 32;
    #pragma unroll
    for (int d = 0; d < 32; ++d) Mrow[d] = f2bf(acc[d] * sinv[d]);
}

// ---------------- K6: fused q-GEMM + softmax + M@q + epilogue ----------
// grid (64 coltiles, 16 b), 512 threads = 8 waves; wave = head = 32 rows.
// ONE 32KB LDS buffer: xn B-tile staged once (swizzled), consumed by GEMM1,
// then overlaid with softmaxed q (barrier-fenced), consumed by GEMM2.
// Natural VGPR ~60 (<=64) + 35KB LDS -> 4 blocks/CU (do NOT add a
// min-waves clamp: R8's (512,8) forced VGPR=32 and spilled, 58->148us).
__global__ __launch_bounds__(512) void k_qfinal(const ushort* __restrict__ Wp,
                                                const ushort* __restrict__ xnbT,
                                                const ushort* __restrict__ M,
                                                const float* __restrict__ b_out,
                                                const float* __restrict__ g2,
                                                const float* __restrict__ x,
                                                float* __restrict__ out) {
    __shared__ ushort BQ[64 * 256];   // swizzled: byte = (row*512+k*2) ^ ((row&7)<<4)
    __shared__ float ss2[8][64];
    const int b = blockIdx.y, col0 = blockIdx.x * 64;
    const int t = threadIdx.x, l = t & 63, w = t >> 6;
    const int lr = l & 15, grp = l >> 4;
    const ushort* xb = xnbT + (size_t)b * N_ * 256;

    {   // stage xn B-tile: 8 threads/row, 64B each
        int row = t >> 3, seg = t & 7;
        const uint4* src = (const uint4*)(xb + (size_t)(col0 + row) * 256 + seg * 32);
        uint base = (uint)(row * 512 + seg * 64);
        uint sw = (uint)((row & 7) << 4);
        #pragma unroll
        for (int i = 0; i < 4; ++i)
            *(uint4*)((char*)BQ + ((base + i * 16) ^ sw)) = src[i];
    }
    __syncthreads();

    // ---- GEMM1: q = Wq @ xn (wave w -> rows w*32..w*32+31) ----
    f32x4 acc[2][4] = {};
    for (int k0 = 0; k0 < 256; k0 += 32) {
        bf16x8 af[2], bf[4];
        #pragma unroll
        for (int m = 0; m < 2; ++m)
            af[m] = *(const bf16x8*)(Wp + (size_t)(w * 32 + m * 16 + lr) * 256 + k0 + grp * 8);
        #pragma unroll
        for (int n = 0; n < 4; ++n) {
            int row = n * 16 + lr;
            uint off = (uint)(row * 512 + (k0 + grp * 8) * 2) ^ (uint)((row & 7) << 4);
            bf[n] = *(const bf16x8*)((const char*)BQ + off);
        }
        #pragma unroll
        for (int m = 0; m < 2; ++m)
            #pragma unroll
            for (int n = 0; n < 4; ++n)
                acc[m][n] = __builtin_amdgcn_mfma_f32_16x16x32_bf16(af[m], bf[n], acc[m][n], 0, 0, 0);
    }
    __syncthreads();   // all GEMM1 reads of BQ (xn) complete

    // ---- per-head softmax over d (wave = head), overlay q into BQ ----
    #pragma unroll
    for (int n = 0; n < 4; ++n) {
        float f[2][4];
        #pragma unroll
        for (int m = 0; m < 2; ++m)
            #pragma unroll
            for (int r = 0; r < 4; ++r) f[m][r] = acc[m][n][r];
        float mx = -1e30f;
        #pragma unroll
        for (int r = 0; r < 4; ++r) mx = fmaxf(mx, fmaxf(f[0][r], f[1][r]));
        mx = fmaxf(mx, __shfl_xor(mx, 16));
        mx = fmaxf(mx, __shfl_xor(mx, 32));
        float s = 0.f;
        #pragma unroll
        for (int r = 0; r < 4; ++r) {
            f[0][r] = __expf(f[0][r] - mx); s += f[0][r];
            f[1][r] = __expf(f[1][r] - mx); s += f[1][r];
        }
        s += __shfl_xor(s, 16); s += __shfl_xor(s, 32);
        float inv = 1.f / s;
        int cl = n * 16 + lr;
        #pragma unroll
        for (int m = 0; m < 2; ++m) {
            int d = w * 32 + m * 16 + grp * 4;
            uint2 pk;
            pk.x = (uint)f2bf(f[m][0] * inv) | ((uint)f2bf(f[m][1] * inv) << 16);
            pk.y = (uint)f2bf(f[m][2] * inv) | ((uint)f2bf(f[m][3] * inv) << 16);
            uint off = (uint)(cl * 512 + d * 2) ^ (uint)((cl & 7) << 4);
            *(uint2*)((char*)BQ + off) = pk;
        }
    }
    __syncthreads();   // all waves' q visible

    // ---- GEMM2: out = M @ q ----
    f32x4 acc2[2][4] = {};
    const ushort* Mb = M + (size_t)b * 256 * 256;
    for (int k0 = 0; k0 < 256; k0 += 32) {
        bf16x8 af[2], bq[4];
        #pragma unroll
        for (int m = 0; m < 2; ++m)
            af[m] = *(const bf16x8*)(Mb + (size_t)(w * 32 + m * 16 + lr) * 256 + k0 + grp * 8);
        #pragma unroll
        for (int n = 0; n < 4; ++n) {
            int row = n * 16 + lr;
            uint off = (uint)(row * 512 + (k0 + grp * 8) * 2) ^ (uint)((row & 7) << 4);
            bq[n] = *(const bf16x8*)((const char*)BQ + off);
        }
        #pragma unroll
        for (int m = 0; m < 2; ++m)
            #pragma unroll
            for (int n = 0; n < 4; ++n)
                acc2[m][n] = __builtin_amdgcn_mfma_f32_16x16x32_bf16(af[m], bq[n], acc2[m][n], 0, 0, 0);
    }

    // ---- epilogue: +b_out, column sum-of-squares over 256 rows ----
    #pragma unroll
    for (int n = 0; n < 4; ++n) {
        float local = 0.f;
        #pragma unroll
        for (int m = 0; m < 2; ++m) {
            int obase = w * 32 + m * 16 + grp * 4;
            #pragma unroll
            for (int r = 0; r < 4; ++r) {
                float f = acc2[m][n][r] + b_out[obase + r];
                acc2[m][n][r] = f;
                local += f * f;
            }
        }
        local += __shfl_xor(local, 16);
        local += __shfl_xor(local, 32);
        if (grp == 0) ss2[w][n * 16 + lr] = local;
    }
    __syncthreads();
    const float* xb2 = x + (size_t)b * C_ * N_;
    float* ob = out + (size_t)b * C_ * N_;
    #pragma unroll
    for (int n = 0; n < 4; ++n) {
        int cl = n * 16 + lr;
        int cg = col0 + cl;
        float tot = ss2[0][cl] + ss2[1][cl] + ss2[2][cl] + ss2[3][cl]
                  + ss2[4][cl] + ss2[5][cl] + ss2[6][cl] + ss2[7][cl];
        float rs = 16.f / fmaxf(sqrtf(tot), EPS_);
        #pragma unroll
        for (int m = 0; m < 2; ++m) {
            int obase = w * 32 + m * 16 + grp * 4;
            #pragma unroll
            for (int r = 0; r < 4; ++r) {
                int o = obase + r;
                ob[(size_t)o * N_ + cg] = acc2[m][n][r] * rs * g2[o] + xb2[(size_t)o * N_ + cg];
            }
        }
    }
}

extern "C" void kernel_launch(void* const* d_in, const int* in_sizes, int n_in,
                              void* d_out, int out_size, void* d_ws, size_t ws_size,
                              hipStream_t stream) {
    const float* x     = (const float*)d_in[0];
    const float* g1    = (const float*)d_in[1];
    const float* w_qkv = (const float*)d_in[2];
    const float* w_out = (const float*)d_in[3];
    const float* b_out = (const float*)d_in[4];
    const float* g2    = (const float*)d_in[5];
    float* out = (float*)d_out;
    char* ws = (char*)d_ws;

    ushort* Wp     = (ushort*)(ws + 0);          //    393216 B
    float*  ctxp   = (float*)(ws + 393216);      //   2097152 B
    float*  sums_p = (float*)(ws + 2490368);     //     65536 B
    ushort* Mm     = (ushort*)(ws + 2555904);    //   2097152 B
    ushort* xnbT   = (ushort*)(ws + 4653056);    //  33554432 B
    ushort* kv     = (ushort*)(ws + 38207488);   //  67108864 B (total 100.4 MB)

    k_prep<<<768, 256, 0, stream>>>(w_qkv, g1, Wp);
    k_xconv<<<dim3(64, 16), 256, 0, stream>>>(x, xnbT);
    k_gemm<<<dim3(32, 4, 16), 256, 0, stream>>>(Wp, xnbT, kv);
    k_ctxpart<<<dim3(128, 4), 256, 0, stream>>>(kv, ctxp, sums_p);
    k_fold<<<128, 256, 0, stream>>>(w_out, ctxp, sums_p, Mm);
    k_qfinal<<<dim3(64, 16), 512, 0, stream>>>(Wp, xnbT, Mm, b_out, g2, x, out);
}

// Round 10
// 146.528 us; speedup vs baseline: 1.5938x; 1.0597x over previous
//
#include <hip/hip_runtime.h>
#include <math.h>

// LinearAttention: B=16, C=256, H=W=64 (N=4096), 8 heads x 32 dim.
// R1: k_fold -> block-per-(b,h) LDS kernel.
// R2: ctx via MFMA; R3: xnbT pre-transpose (rinv folded).
// R6: k_qfinal fuses q-GEMM + softmax + M@q + epilogue.
// R7-R9: k_qfinal invariant at ~58us across LDS/barrier/occupancy variants
//     -> pipeline is globally bound on intermediate HBM bytes (~416MB).
// R10: k_kvctx fuses kv-GEMM + ctxpart (deletes kv 64MB write + 64MB read).
//     Orientation-swapped GEMM (C[n][o]) makes P/V LDS stores packed uint2;
//     per-head ctx + psum via in-LDS MFMA (ones-vector trick). 148KB dynamic
//     LDS. ctxp now 32 slices; k_fold loops 32. ws 100MB -> 53MB.

#define B_ 16
#define C_ 256
#define N_ 4096
#define SCALE_ 0.17677669529663687f
#define EPS_ 1e-12f

typedef __attribute__((ext_vector_type(8))) short bf16x8;
typedef __attribute__((ext_vector_type(4))) float f32x4;

__device__ __forceinline__ ushort f2bf(float f) {
    union { float f; uint u; } x; x.f = f;
    uint r = (x.u + 0x7FFFu + ((x.u >> 16) & 1u)) >> 16;
    return (ushort)r;
}
__device__ __forceinline__ float bf2f(ushort s) {
    union { uint u; float f; } x; x.u = ((uint)s) << 16;
    return x.f;
}

// ---------------- K1: W' = w_qkv * g1 -> bf16 ----------------
__global__ __launch_bounds__(256) void k_prep(const float* __restrict__ w_qkv,
                                              const float* __restrict__ g1,
                                              ushort* __restrict__ Wp) {
    int o = blockIdx.x, c = threadIdx.x;
    Wp[(size_t)o * 256 + c] = f2bf(w_qkv[(size_t)o * 256 + c] * g1[c]);
}

// ---------------- K2: xnbT[b][n][c] = bf16(x[b][c][n] * rinv[b][n]) -------
__global__ __launch_bounds__(256) void k_xconv(const float* __restrict__ x,
                                               ushort* __restrict__ xnbT) {
    __shared__ float ssp[4][64];
    __shared__ float rinv_s[64];
    __shared__ ushort T[64][268];
    int b = blockIdx.y, n0 = blockIdx.x * 64;
    const float* xb = x + (size_t)b * C_ * N_ + n0;
    int t = threadIdx.x;
    int nl = t & 63, cg = t >> 6;
    float ss = 0.f;
    #pragma unroll 8
    for (int i = 0; i < 64; ++i) {
        float v = xb[(size_t)(cg * 64 + i) * N_ + nl];
        ss += v * v;
    }
    ssp[cg][nl] = ss;
    __syncthreads();
    if (t < 64)
        rinv_s[t] = 16.f / fmaxf(sqrtf(ssp[0][t] + ssp[1][t] + ssp[2][t] + ssp[3][t]), EPS_);
    __syncthreads();
    float rv = rinv_s[nl];
    #pragma unroll 8
    for (int i = 0; i < 64; ++i) {
        int c = cg * 64 + i;
        T[nl][c] = f2bf(xb[(size_t)c * N_ + nl] * rv);   // L2-hot re-read
    }
    __syncthreads();
    int j = t >> 2, ch = t & 3;
    ushort* orow = xnbT + ((size_t)b * N_ + n0 + j) * 256 + ch * 64;
    #pragma unroll
    for (int i = 0; i < 8; ++i)
        *(uint2*)&orow[i * 8] = *(const uint2*)&T[j][ch * 64 + i * 8],
        *(uint2*)&orow[i * 8 + 4] = *(const uint2*)&T[j][ch * 64 + i * 8 + 4];
}

// ---------------- K3: fused kv-GEMM + exp + ctx partial -------------------
// grid (32 n-slices, 16 b), 512 threads = 8 waves. Per block:
//   stage xn[128n][256c] (swz) -> pass0: C[n][d]=xn@Wk^T -> P=exp (LDS)
//   -> pass1: C[n][e]=xn@Wv^T -> V overlaid on xn LDS
//   -> per-head (wave=head) ctx[d][e] = mfma(P,V), psum = mfma(P,ones)
// Dynamic LDS 148KB: Asub 20KB | BQ 64KB (xn then V) | P 64KB.
__global__ __launch_bounds__(512) void k_kvctx(const ushort* __restrict__ Wp,
                                               const ushort* __restrict__ xnbT,
                                               float* __restrict__ ctxp,
                                               float* __restrict__ sums_p) {
    extern __shared__ char lds[];
    ushort (*Asub)[40] = (ushort(*)[40])lds;          // 256 x 40 = 20480 B
    char* BQ = lds + 20480;                           // 65536 B
    char* P  = lds + 86016;                           // 65536 B
    const int b = blockIdx.y, s = blockIdx.x;
    const int col0 = s * 128;
    const int t = threadIdx.x, l = t & 63, w = t >> 6;
    const int lr = l & 15, grp = l >> 4;
    const int wn = w & 3, wo = w >> 2;   // wave n-group (32 rows), o-group (128 cols)
    const ushort* xb = xnbT + (size_t)b * N_ * 256;

    {   // stage xn tile [128][256] swizzled (rows 512B, byte ^= (row&7)<<4)
        int row = t >> 2, seg = t & 3;
        const uint4* src = (const uint4*)(xb + (size_t)(col0 + row) * 256 + seg * 64);
        uint base = (uint)(row * 512 + seg * 128);
        uint sw = (uint)((row & 7) << 4);
        #pragma unroll
        for (int i = 0; i < 8; ++i)
            *(uint4*)(BQ + ((base + i * 16) ^ sw)) = src[i];
    }

    #pragma unroll
    for (int p = 0; p < 2; ++p) {
        f32x4 acc[2][8] = {};
        for (int k0 = 0; k0 < 256; k0 += 32) {
            {   // stage Wkv o-rows (k rows p=0: Wp 256.., v rows p=1: Wp 512..)
                int r = t >> 1, ko = (t & 1) * 16;
                const uint4* sa = (const uint4*)(Wp + (size_t)(256 + p * 256 + r) * 256 + k0 + ko);
                *(uint4*)&Asub[r][ko]     = sa[0];
                *(uint4*)&Asub[r][ko + 8] = sa[1];
            }
            __syncthreads();
            bf16x8 ax[2], bw[8];
            #pragma unroll
            for (int m = 0; m < 2; ++m) {
                int row = wn * 32 + m * 16 + lr;
                uint off = (uint)(row * 512 + (k0 + grp * 8) * 2) ^ (uint)((row & 7) << 4);
                ax[m] = *(const bf16x8*)(BQ + off);
            }
            #pragma unroll
            for (int nf = 0; nf < 8; ++nf)
                bw[nf] = *(const bf16x8*)&Asub[wo * 128 + nf * 16 + lr][grp * 8];
            #pragma unroll
            for (int m = 0; m < 2; ++m)
                #pragma unroll
                for (int nf = 0; nf < 8; ++nf)
                    acc[m][nf] = __builtin_amdgcn_mfma_f32_16x16x32_bf16(ax[m], bw[nf], acc[m][nf], 0, 0, 0);
            __syncthreads();
        }
        if (p == 0) {
            // P[d][n] = bf16(exp(logit)), rows 256B, byte ^= (d&7)<<4
            #pragma unroll
            for (int nf = 0; nf < 8; ++nf) {
                int d = wo * 128 + nf * 16 + lr;
                uint sw = (uint)((d & 7) << 4);
                #pragma unroll
                for (int m = 0; m < 2; ++m) {
                    int n0 = wn * 32 + m * 16 + grp * 4;
                    uint2 pk;
                    pk.x = (uint)f2bf(__expf(acc[m][nf][0])) | ((uint)f2bf(__expf(acc[m][nf][1])) << 16);
                    pk.y = (uint)f2bf(__expf(acc[m][nf][2])) | ((uint)f2bf(__expf(acc[m][nf][3])) << 16);
                    *(uint2*)(P + (((uint)(d * 256 + n0 * 2)) ^ sw)) = pk;
                }
            }
        } else {
            // V[e][n] overlaid onto BQ (xn dead after pass-1's trailing barrier)
            #pragma unroll
            for (int nf = 0; nf < 8; ++nf) {
                int e = wo * 128 + nf * 16 + lr;
                uint sw = (uint)((e & 7) << 4);
                #pragma unroll
                for (int m = 0; m < 2; ++m) {
                    int n0 = wn * 32 + m * 16 + grp * 4;
                    uint2 pk;
                    pk.x = (uint)f2bf(acc[m][nf][0]) | ((uint)f2bf(acc[m][nf][1]) << 16);
                    pk.y = (uint)f2bf(acc[m][nf][2]) | ((uint)f2bf(acc[m][nf][3]) << 16);
                    *(uint2*)(BQ + (((uint)(e * 256 + n0 * 2)) ^ sw)) = pk;
                }
            }
        }
    }
    __syncthreads();   // P and V fully visible

    // per-head ctx: wave = head
    const int h = w;
    f32x4 c3[2][2] = {};
    f32x4 cS[2] = {};
    bf16x8 ones;
    #pragma unroll
    for (int j = 0; j < 8; ++j) ones[j] = (short)0x3F80;   // bf16 1.0
    #pragma unroll
    for (int ks = 0; ks < 4; ++ks) {
        int n0 = ks * 32 + grp * 8;
        bf16x8 pA[2], vB[2];
        #pragma unroll
        for (int df = 0; df < 2; ++df) {
            int d = h * 32 + df * 16 + lr;
            pA[df] = *(const bf16x8*)(P + (((uint)(d * 256 + n0 * 2)) ^ ((uint)((d & 7) << 4))));
        }
        #pragma unroll
        for (int ef = 0; ef < 2; ++ef) {
            int e = h * 32 + ef * 16 + lr;
            vB[ef] = *(const bf16x8*)(BQ + (((uint)(e * 256 + n0 * 2)) ^ ((uint)((e & 7) << 4))));
        }
        #pragma unroll
        for (int df = 0; df < 2; ++df) {
            #pragma unroll
            for (int ef = 0; ef < 2; ++ef)
                c3[df][ef] = __builtin_amdgcn_mfma_f32_16x16x32_bf16(pA[df], vB[ef], c3[df][ef], 0, 0, 0);
            cS[df] = __builtin_amdgcn_mfma_f32_16x16x32_bf16(pA[df], ones, cS[df], 0, 0, 0);
        }
    }
    int bh = b * 8 + h;
    size_t base = ((size_t)s * 128 + bh) * 32;
    #pragma unroll
    for (int df = 0; df < 2; ++df) {
        #pragma unroll
        for (int ef = 0; ef < 2; ++ef)
            #pragma unroll
            for (int r = 0; r < 4; ++r)
                ctxp[(base + df * 16 + grp * 4 + r) * 32 + ef * 16 + lr] = c3[df][ef][r];
        if (lr == 0)
            #pragma unroll
            for (int r = 0; r < 4; ++r)
                sums_p[base + df * 16 + grp * 4 + r] = cS[df][r];
    }
}

// ---------------- K5: M[b][o][h*32+d] = SCALE/stot[d] * sum_e w_out.ctx ----
__global__ __launch_bounds__(256) void k_fold(const float* __restrict__ w_out,
                                              const float* __restrict__ ctxp,
                                              const float* __restrict__ sums_p,
                                              ushort* __restrict__ M) {
    __shared__ float cn[32][33];
    __shared__ float sinv[32];
    int bh = blockIdx.x;
    int b = bh >> 3, h = bh & 7;
    int t = threadIdx.x;
    if (t < 32) {
        float st = 0.f;
        #pragma unroll 8
        for (int s = 0; s < 32; ++s) st += sums_p[(size_t)(s * 128 + bh) * 32 + t];
        sinv[t] = SCALE_ / st;
    }
    #pragma unroll
    for (int i = t; i < 1024; i += 256) {
        int d = i >> 5, e = i & 31;
        float cv = 0.f;
        #pragma unroll 8
        for (int s = 0; s < 32; ++s)
            cv += ctxp[((size_t)(s * 128 + bh) * 32 + d) * 32 + e];
        cn[e][d] = cv;
    }
    __syncthreads();
    float wreg[32];
    const float* wr = w_out + (size_t)t * 256 + h * 32;
    #pragma unroll
    for (int e = 0; e < 32; e += 4) {
        float4 wv = *(const float4*)&wr[e];
        wreg[e] = wv.x; wreg[e + 1] = wv.y; wreg[e + 2] = wv.z; wreg[e + 3] = wv.w;
    }
    float acc[32] = {};
    #pragma unroll
    for (int e = 0; e < 32; ++e) {
        float we = wreg[e];
        #pragma unroll
        for (int d = 0; d < 32; ++d) acc[d] += we * cn[e][d];
    }
    ushort* Mrow = M + ((size_t)b * 256 + t) * 256 + h * 32;
    #pragma unroll
    for (int d = 0; d < 32; ++d) Mrow[d] = f2bf(acc[d] * sinv[d]);
}

// ---------------- K6: fused q-GEMM + softmax + M@q + epilogue ----------
// (unchanged R9: 64-col tiles, BQ overlay, natural VGPR~60)
__global__ __launch_bounds__(512) void k_qfinal(const ushort* __restrict__ Wp,
                                                const ushort* __restrict__ xnbT,
                                                const ushort* __restrict__ M,
                                                const float* __restrict__ b_out,
                                                const float* __restrict__ g2,
                                                const float* __restrict__ x,
                                                float* __restrict__ out) {
    __shared__ ushort BQ[64 * 256];   // swizzled: byte = (row*512+k*2) ^ ((row&7)<<4)
    __shared__ float ss2[8][64];
    const int b = blockIdx.y, col0 = blockIdx.x * 64;
    const int t = threadIdx.x, l = t & 63, w = t >> 6;
    const int lr = l & 15, grp = l >> 4;
    const ushort* xb = xnbT + (size_t)b * N_ * 256;

    {   // stage xn B-tile: 8 threads/row, 64B each
        int row = t >> 3, seg = t & 7;
        const uint4* src = (const uint4*)(xb + (size_t)(col0 + row) * 256 + seg * 32);
        uint base = (uint)(row * 512 + seg * 64);
        uint sw = (uint)((row & 7) << 4);
        #pragma unroll
        for (int i = 0; i < 4; ++i)
            *(uint4*)((char*)BQ + ((base + i * 16) ^ sw)) = src[i];
    }
    __syncthreads();

    // ---- GEMM1: q = Wq @ xn (wave w -> rows w*32..w*32+31) ----
    f32x4 acc[2][4] = {};
    for (int k0 = 0; k0 < 256; k0 += 32) {
        bf16x8 af[2], bf[4];
        #pragma unroll
        for (int m = 0; m < 2; ++m)
            af[m] = *(const bf16x8*)(Wp + (size_t)(w * 32 + m * 16 + lr) * 256 + k0 + grp * 8);
        #pragma unroll
        for (int n = 0; n < 4; ++n) {
            int row = n * 16 + lr;
            uint off = (uint)(row * 512 + (k0 + grp * 8) * 2) ^ (uint)((row & 7) << 4);
            bf[n] = *(const bf16x8*)((const char*)BQ + off);
        }
        #pragma unroll
        for (int m = 0; m < 2; ++m)
            #pragma unroll
            for (int n = 0; n < 4; ++n)
                acc[m][n] = __builtin_amdgcn_mfma_f32_16x16x32_bf16(af[m], bf[n], acc[m][n], 0, 0, 0);
    }
    __syncthreads();   // all GEMM1 reads of BQ (xn) complete

    // ---- per-head softmax over d (wave = head), overlay q into BQ ----
    #pragma unroll
    for (int n = 0; n < 4; ++n) {
        float f[2][4];
        #pragma unroll
        for (int m = 0; m < 2; ++m)
            #pragma unroll
            for (int r = 0; r < 4; ++r) f[m][r] = acc[m][n][r];
        float mx = -1e30f;
        #pragma unroll
        for (int r = 0; r < 4; ++r) mx = fmaxf(mx, fmaxf(f[0][r], f[1][r]));
        mx = fmaxf(mx, __shfl_xor(mx, 16));
        mx = fmaxf(mx, __shfl_xor(mx, 32));
        float s = 0.f;
        #pragma unroll
        for (int r = 0; r < 4; ++r) {
            f[0][r] = __expf(f[0][r] - mx); s += f[0][r];
            f[1][r] = __expf(f[1][r] - mx); s += f[1][r];
        }
        s += __shfl_xor(s, 16); s += __shfl_xor(s, 32);
        float inv = 1.f / s;
        int cl = n * 16 + lr;
        #pragma unroll
        for (int m = 0; m < 2; ++m) {
            int d = w * 32 + m * 16 + grp * 4;
            uint2 pk;
            pk.x = (uint)f2bf(f[m][0] * inv) | ((uint)f2bf(f[m][1] * inv) << 16);
            pk.y = (uint)f2bf(f[m][2] * inv) | ((uint)f2bf(f[m][3] * inv) << 16);
            uint off = (uint)(cl * 512 + d * 2) ^ (uint)((cl & 7) << 4);
            *(uint2*)((char*)BQ + off) = pk;
        }
    }
    __syncthreads();   // all waves' q visible

    // ---- GEMM2: out = M @ q ----
    f32x4 acc2[2][4] = {};
    const ushort* Mb = M + (size_t)b * 256 * 256;
    for (int k0 = 0; k0 < 256; k0 += 32) {
        bf16x8 af[2], bq[4];
        #pragma unroll
        for (int m = 0; m < 2; ++m)
            af[m] = *(const bf16x8*)(Mb + (size_t)(w * 32 + m * 16 + lr) * 256 + k0 + grp * 8);
        #pragma unroll
        for (int n = 0; n < 4; ++n) {
            int row = n * 16 + lr;
            uint off = (uint)(row * 512 + (k0 + grp * 8) * 2) ^ (uint)((row & 7) << 4);
            bq[n] = *(const bf16x8*)((const char*)BQ + off);
        }
        #pragma unroll
        for (int m = 0; m < 2; ++m)
            #pragma unroll
            for (int n = 0; n < 4; ++n)
                acc2[m][n] = __builtin_amdgcn_mfma_f32_16x16x32_bf16(af[m], bq[n], acc2[m][n], 0, 0, 0);
    }

    // ---- epilogue: +b_out, column sum-of-squares over 256 rows ----
    #pragma unroll
    for (int n = 0; n < 4; ++n) {
        float local = 0.f;
        #pragma unroll
        for (int m = 0; m < 2; ++m) {
            int obase = w * 32 + m * 16 + grp * 4;
            #pragma unroll
            for (int r = 0; r < 4; ++r) {
                float f = acc2[m][n][r] + b_out[obase + r];
                acc2[m][n][r] = f;
                local += f * f;
            }
        }
        local += __shfl_xor(local, 16);
        local += __shfl_xor(local, 32);
        if (grp == 0) ss2[w][n * 16 + lr] = local;
    }
    __syncthreads();
    const float* xb2 = x + (size_t)b * C_ * N_;
    float* ob = out + (size_t)b * C_ * N_;
    #pragma unroll
    for (int n = 0; n < 4; ++n) {
        int cl = n * 16 + lr;
        int cg = col0 + cl;
        float tot = ss2[0][cl] + ss2[1][cl] + ss2[2][cl] + ss2[3][cl]
                  + ss2[4][cl] + ss2[5][cl] + ss2[6][cl] + ss2[7][cl];
        float rs = 16.f / fmaxf(sqrtf(tot), EPS_);
        #pragma unroll
        for (int m = 0; m < 2; ++m) {
            int obase = w * 32 + m * 16 + grp * 4;
            #pragma unroll
            for (int r = 0; r < 4; ++r) {
                int o = obase + r;
                ob[(size_t)o * N_ + cg] = acc2[m][n][r] * rs * g2[o] + xb2[(size_t)o * N_ + cg];
            }
        }
    }
}

extern "C" void kernel_launch(void* const* d_in, const int* in_sizes, int n_in,
                              void* d_out, int out_size, void* d_ws, size_t ws_size,
                              hipStream_t stream) {
    const float* x     = (const float*)d_in[0];
    const float* g1    = (const float*)d_in[1];
    const float* w_qkv = (const float*)d_in[2];
    const float* w_out = (const float*)d_in[3];
    const float* b_out = (const float*)d_in[4];
    const float* g2    = (const float*)d_in[5];
    float* out = (float*)d_out;
    char* ws = (char*)d_ws;

    ushort* Wp     = (ushort*)(ws + 0);          //    393216 B
    float*  ctxp   = (float*)(ws + 393216);      //  16777216 B (32 slices)
    float*  sums_p = (float*)(ws + 17170432);    //    524288 B
    ushort* Mm     = (ushort*)(ws + 17694720);   //   2097152 B
    ushort* xnbT   = (ushort*)(ws + 19791872);   //  33554432 B (total ~53.3 MB)

    // allow >64KB dynamic LDS for k_kvctx (gfx950 has 160KB/CU)
    hipFuncSetAttribute((const void*)k_kvctx,
                        hipFuncAttributeMaxDynamicSharedMemorySize, 151552);

    k_prep<<<768, 256, 0, stream>>>(w_qkv, g1, Wp);
    k_xconv<<<dim3(64, 16), 256, 0, stream>>>(x, xnbT);
    k_kvctx<<<dim3(32, 16), 512, 151552, stream>>>(Wp, xnbT, ctxp, sums_p);
    k_fold<<<128, 256, 0, stream>>>(w_out, ctxp, sums_p, Mm);
    k_qfinal<<<dim3(64, 16), 512, 0, stream>>>(Wp, xnbT, Mm, b_out, g2, x, out);
}

// Round 11
// 134.226 us; speedup vs baseline: 1.7399x; 1.0916x over previous
//
#include <hip/hip_runtime.h>
#include <math.h>

// LinearAttention: B=16, C=256, H=W=64 (N=4096), 8 heads x 32 dim.
// R1: k_fold -> block-per-(b,h) LDS kernel.
// R2: ctx via MFMA; R3: xnbT pre-transpose (rinv folded).
// R6: k_qfinal fuses q-GEMM + softmax + M@q + epilogue.
// R7-R9: k_qfinal ~58us invariant -> pipeline HBM-bytes bound.
// R10: k_kvctx fuses kv-GEMM + exp + ctx partial (kv round-trip deleted).
// R11: xnbT + k_xconv DELETED: both k_kvctx and k_qfinal recompute
//      xn = bf16(x*rinv) from raw x in a one-time prologue (coalesced
//      sumsq -> rinv -> scale+pack into the same swizzled BQ layout).
//      -96MB traffic, -1 launch. ws ~19.8MB.

#define B_ 16
#define C_ 256
#define N_ 4096
#define SCALE_ 0.17677669529663687f
#define EPS_ 1e-12f

typedef __attribute__((ext_vector_type(8))) short bf16x8;
typedef __attribute__((ext_vector_type(4))) float f32x4;

__device__ __forceinline__ ushort f2bf(float f) {
    union { float f; uint u; } x; x.f = f;
    uint r = (x.u + 0x7FFFu + ((x.u >> 16) & 1u)) >> 16;
    return (ushort)r;
}
__device__ __forceinline__ float bf2f(ushort s) {
    union { uint u; float f; } x; x.u = ((uint)s) << 16;
    return x.f;
}

// ---------------- K1: W' = w_qkv * g1 -> bf16 ----------------
__global__ __launch_bounds__(256) void k_prep(const float* __restrict__ w_qkv,
                                              const float* __restrict__ g1,
                                              ushort* __restrict__ Wp) {
    int o = blockIdx.x, c = threadIdx.x;
    Wp[(size_t)o * 256 + c] = f2bf(w_qkv[(size_t)o * 256 + c] * g1[c]);
}

// ---------------- K2: fused rnorm + kv-GEMM + exp + ctx partial -----------
// grid (32 n-slices, 16 b), 512 threads = 8 waves. Per block:
//   prologue: read x[c][n-tile] fp32, per-n rinv, xn=bf16(x*rinv) -> BQ (swz)
//   pass0: C[n][d]=xn@Wk^T -> P=exp (LDS); pass1: C[n][e]=xn@Wv^T -> V on BQ
//   per-head (wave=head) ctx[d][e] = mfma(P,V), psum = mfma(P,ones)
// Dynamic LDS 154112: Asub 20K | BQ 64K (xn then V) | P 64K | aux 2.5K.
__global__ __launch_bounds__(512) void k_kvctx(const ushort* __restrict__ Wp,
                                               const float* __restrict__ x,
                                               float* __restrict__ ctxp,
                                               float* __restrict__ sums_p) {
    extern __shared__ char lds[];
    ushort (*Asub)[40] = (ushort(*)[40])lds;          // 20480 B
    char* BQ = lds + 20480;                           // 65536 B
    char* P  = lds + 86016;                           // 65536 B
    float* sspA  = (float*)(lds + 151552);            //  2048 B
    float* rinvA = (float*)(lds + 153600);            //   512 B
    const int b = blockIdx.y, s = blockIdx.x;
    const int col0 = s * 128;
    const int t = threadIdx.x, l = t & 63, w = t >> 6;
    const int lr = l & 15, grp = l >> 4;
    const int wn = w & 3, wo = w >> 2;
    const float* xb = x + (size_t)b * C_ * N_ + col0;

    {   // prologue A: per-column sumsq (coalesced: lane = column)
        int col = t & 127, rg = t >> 7;
        float ss = 0.f;
        #pragma unroll 8
        for (int i = 0; i < 64; ++i) {
            float v = xb[(size_t)(rg * 64 + i) * N_ + col];
            ss += v * v;
        }
        sspA[rg * 128 + col] = ss;
    }
    __syncthreads();
    if (t < 128)
        rinvA[t] = 16.f / fmaxf(sqrtf(sspA[t] + sspA[128 + t] + sspA[256 + t] + sspA[384 + t]), EPS_);
    __syncthreads();
    {   // prologue B: xn = bf16(x*rinv) -> BQ[col][c], swz byte ^= (col&7)<<4
        int col = t & 127, rg = t >> 7;
        float rv = rinvA[col];
        uint sw = (uint)((col & 7) << 4);
        #pragma unroll
        for (int i = 0; i < 16; ++i) {
            int c = rg * 64 + i * 4;
            uint2 pk;
            pk.x = (uint)f2bf(xb[(size_t)c * N_ + col] * rv)
                 | ((uint)f2bf(xb[(size_t)(c + 1) * N_ + col] * rv) << 16);
            pk.y = (uint)f2bf(xb[(size_t)(c + 2) * N_ + col] * rv)
                 | ((uint)f2bf(xb[(size_t)(c + 3) * N_ + col] * rv) << 16);
            *(uint2*)(BQ + (((uint)(col * 512 + c * 2)) ^ sw)) = pk;
        }
    }

    #pragma unroll
    for (int p = 0; p < 2; ++p) {
        f32x4 acc[2][8] = {};
        for (int k0 = 0; k0 < 256; k0 += 32) {
            {   // stage Wkv o-rows (p=0: Wp 256.., p=1: Wp 512..)
                int r = t >> 1, ko = (t & 1) * 16;
                const uint4* sa = (const uint4*)(Wp + (size_t)(256 + p * 256 + r) * 256 + k0 + ko);
                *(uint4*)&Asub[r][ko]     = sa[0];
                *(uint4*)&Asub[r][ko + 8] = sa[1];
            }
            __syncthreads();   // first iter also fences prologue BQ writes
            bf16x8 ax[2], bw[8];
            #pragma unroll
            for (int m = 0; m < 2; ++m) {
                int row = wn * 32 + m * 16 + lr;
                uint off = (uint)(row * 512 + (k0 + grp * 8) * 2) ^ (uint)((row & 7) << 4);
                ax[m] = *(const bf16x8*)(BQ + off);
            }
            #pragma unroll
            for (int nf = 0; nf < 8; ++nf)
                bw[nf] = *(const bf16x8*)&Asub[wo * 128 + nf * 16 + lr][grp * 8];
            #pragma unroll
            for (int m = 0; m < 2; ++m)
                #pragma unroll
                for (int nf = 0; nf < 8; ++nf)
                    acc[m][nf] = __builtin_amdgcn_mfma_f32_16x16x32_bf16(ax[m], bw[nf], acc[m][nf], 0, 0, 0);
            __syncthreads();
        }
        if (p == 0) {
            // P[d][n] = bf16(exp(logit)), rows 256B, byte ^= (d&7)<<4
            #pragma unroll
            for (int nf = 0; nf < 8; ++nf) {
                int d = wo * 128 + nf * 16 + lr;
                uint sw = (uint)((d & 7) << 4);
                #pragma unroll
                for (int m = 0; m < 2; ++m) {
                    int n0 = wn * 32 + m * 16 + grp * 4;
                    uint2 pk;
                    pk.x = (uint)f2bf(__expf(acc[m][nf][0])) | ((uint)f2bf(__expf(acc[m][nf][1])) << 16);
                    pk.y = (uint)f2bf(__expf(acc[m][nf][2])) | ((uint)f2bf(__expf(acc[m][nf][3])) << 16);
                    *(uint2*)(P + (((uint)(d * 256 + n0 * 2)) ^ sw)) = pk;
                }
            }
        } else {
            // V[e][n] overlaid onto BQ (xn dead after pass-1 trailing barrier)
            #pragma unroll
            for (int nf = 0; nf < 8; ++nf) {
                int e = wo * 128 + nf * 16 + lr;
                uint sw = (uint)((e & 7) << 4);
                #pragma unroll
                for (int m = 0; m < 2; ++m) {
                    int n0 = wn * 32 + m * 16 + grp * 4;
                    uint2 pk;
                    pk.x = (uint)f2bf(acc[m][nf][0]) | ((uint)f2bf(acc[m][nf][1]) << 16);
                    pk.y = (uint)f2bf(acc[m][nf][2]) | ((uint)f2bf(acc[m][nf][3]) << 16);
                    *(uint2*)(BQ + (((uint)(e * 256 + n0 * 2)) ^ sw)) = pk;
                }
            }
        }
    }
    __syncthreads();   // P and V fully visible

    // per-head ctx: wave = head
    const int h = w;
    f32x4 c3[2][2] = {};
    f32x4 cS[2] = {};
    bf16x8 ones;
    #pragma unroll
    for (int j = 0; j < 8; ++j) ones[j] = (short)0x3F80;   // bf16 1.0
    #pragma unroll
    for (int ks = 0; ks < 4; ++ks) {
        int n0 = ks * 32 + grp * 8;
        bf16x8 pA[2], vB[2];
        #pragma unroll
        for (int df = 0; df < 2; ++df) {
            int d = h * 32 + df * 16 + lr;
            pA[df] = *(const bf16x8*)(P + (((uint)(d * 256 + n0 * 2)) ^ ((uint)((d & 7) << 4))));
        }
        #pragma unroll
        for (int ef = 0; ef < 2; ++ef) {
            int e = h * 32 + ef * 16 + lr;
            vB[ef] = *(const bf16x8*)(BQ + (((uint)(e * 256 + n0 * 2)) ^ ((uint)((e & 7) << 4))));
        }
        #pragma unroll
        for (int df = 0; df < 2; ++df) {
            #pragma unroll
            for (int ef = 0; ef < 2; ++ef)
                c3[df][ef] = __builtin_amdgcn_mfma_f32_16x16x32_bf16(pA[df], vB[ef], c3[df][ef], 0, 0, 0);
            cS[df] = __builtin_amdgcn_mfma_f32_16x16x32_bf16(pA[df], ones, cS[df], 0, 0, 0);
        }
    }
    int bh = b * 8 + h;
    size_t base = ((size_t)s * 128 + bh) * 32;
    #pragma unroll
    for (int df = 0; df < 2; ++df) {
        #pragma unroll
        for (int ef = 0; ef < 2; ++ef)
            #pragma unroll
            for (int r = 0; r < 4; ++r)
                ctxp[(base + df * 16 + grp * 4 + r) * 32 + ef * 16 + lr] = c3[df][ef][r];
        if (lr == 0)
            #pragma unroll
            for (int r = 0; r < 4; ++r)
                sums_p[base + df * 16 + grp * 4 + r] = cS[df][r];
    }
}

// ---------------- K3: M[b][o][h*32+d] = SCALE/stot[d] * sum_e w_out.ctx ----
__global__ __launch_bounds__(256) void k_fold(const float* __restrict__ w_out,
                                              const float* __restrict__ ctxp,
                                              const float* __restrict__ sums_p,
                                              ushort* __restrict__ M) {
    __shared__ float cn[32][33];
    __shared__ float sinv[32];
    int bh = blockIdx.x;
    int b = bh >> 3, h = bh & 7;
    int t = threadIdx.x;
    if (t < 32) {
        float st = 0.f;
        #pragma unroll 8
        for (int s = 0; s < 32; ++s) st += sums_p[(size_t)(s * 128 + bh) * 32 + t];
        sinv[t] = SCALE_ / st;
    }
    #pragma unroll
    for (int i = t; i < 1024; i += 256) {
        int d = i >> 5, e = i & 31;
        float cv = 0.f;
        #pragma unroll 8
        for (int s = 0; s < 32; ++s)
            cv += ctxp[((size_t)(s * 128 + bh) * 32 + d) * 32 + e];
        cn[e][d] = cv;
    }
    __syncthreads();
    float wreg[32];
    const float* wr = w_out + (size_t)t * 256 + h * 32;
    #pragma unroll
    for (int e = 0; e < 32; e += 4) {
        float4 wv = *(const float4*)&wr[e];
        wreg[e] = wv.x; wreg[e + 1] = wv.y; wreg[e + 2] = wv.z; wreg[e + 3] = wv.w;
    }
    float acc[32] = {};
    #pragma unroll
    for (int e = 0; e < 32; ++e) {
        float we = wreg[e];
        #pragma unroll
        for (int d = 0; d < 32; ++d) acc[d] += we * cn[e][d];
    }
    ushort* Mrow = M + ((size_t)b * 256 + t) * 256 + h * 32;
    #pragma unroll
    for (int d = 0; d < 32; ++d) Mrow[d] = f2bf(acc[d] * sinv[d]);
}

// ---------------- K4: fused rnorm + q-GEMM + softmax + M@q + epilogue -----
// grid (64 coltiles, 16 b), 512 threads = 8 waves; wave = head = 32 rows.
// prologue: x -> rinv -> xn=bf16(x*rinv) into swizzled BQ (reuses ss2 as
// sumsq scratch). GEMM1 -> softmax -> q overlays BQ -> GEMM2 ->
// (+b_out, RMSNorm*g2*16, +x residual from L2-hot x).
__global__ __launch_bounds__(512) void k_qfinal(const ushort* __restrict__ Wp,
                                                const ushort* __restrict__ M,
                                                const float* __restrict__ b_out,
                                                const float* __restrict__ g2,
                                                const float* __restrict__ x,
                                                float* __restrict__ out) {
    __shared__ ushort BQ[64 * 256];   // swizzled: byte = (row*512+k*2) ^ ((row&7)<<4)
    __shared__ float ss2[8][64];      // prologue sumsq scratch, epilogue ssq
    __shared__ float rinvq[64];
    const int b = blockIdx.y, col0 = blockIdx.x * 64;
    const int t = threadIdx.x, l = t & 63, w = t >> 6;
    const int lr = l & 15, grp = l >> 4;
    const float* xb2 = x + (size_t)b * C_ * N_;

    {   // prologue A: per-column sumsq
        int col = t & 63, rg = t >> 6;
        float ss = 0.f;
        #pragma unroll 8
        for (int i = 0; i < 32; ++i) {
            float v = xb2[(size_t)(rg * 32 + i) * N_ + col0 + col];
            ss += v * v;
        }
        ss2[rg][col] = ss;
    }
    __syncthreads();
    if (t < 64) {
        float st = ss2[0][t] + ss2[1][t] + ss2[2][t] + ss2[3][t]
                 + ss2[4][t] + ss2[5][t] + ss2[6][t] + ss2[7][t];
        rinvq[t] = 16.f / fmaxf(sqrtf(st), EPS_);
    }
    __syncthreads();
    {   // prologue B: xn -> BQ
        int col = t & 63, rg = t >> 6;
        float rv = rinvq[col];
        uint sw = (uint)((col & 7) << 4);
        #pragma unroll
        for (int i = 0; i < 8; ++i) {
            int c = rg * 32 + i * 4;
            uint2 pk;
            pk.x = (uint)f2bf(xb2[(size_t)c * N_ + col0 + col] * rv)
                 | ((uint)f2bf(xb2[(size_t)(c + 1) * N_ + col0 + col] * rv) << 16);
            pk.y = (uint)f2bf(xb2[(size_t)(c + 2) * N_ + col0 + col] * rv)
                 | ((uint)f2bf(xb2[(size_t)(c + 3) * N_ + col0 + col] * rv) << 16);
            *(uint2*)((char*)BQ + (((uint)(col * 512 + c * 2)) ^ sw)) = pk;
        }
    }
    __syncthreads();

    // ---- GEMM1: q = Wq @ xn (wave w -> rows w*32..w*32+31) ----
    f32x4 acc[2][4] = {};
    for (int k0 = 0; k0 < 256; k0 += 32) {
        bf16x8 af[2], bf[4];
        #pragma unroll
        for (int m = 0; m < 2; ++m)
            af[m] = *(const bf16x8*)(Wp + (size_t)(w * 32 + m * 16 + lr) * 256 + k0 + grp * 8);
        #pragma unroll
        for (int n = 0; n < 4; ++n) {
            int row = n * 16 + lr;
            uint off = (uint)(row * 512 + (k0 + grp * 8) * 2) ^ (uint)((row & 7) << 4);
            bf[n] = *(const bf16x8*)((const char*)BQ + off);
        }
        #pragma unroll
        for (int m = 0; m < 2; ++m)
            #pragma unroll
            for (int n = 0; n < 4; ++n)
                acc[m][n] = __builtin_amdgcn_mfma_f32_16x16x32_bf16(af[m], bf[n], acc[m][n], 0, 0, 0);
    }
    __syncthreads();   // all GEMM1 reads of BQ (xn) complete

    // ---- per-head softmax over d (wave = head), overlay q into BQ ----
    #pragma unroll
    for (int n = 0; n < 4; ++n) {
        float f[2][4];
        #pragma unroll
        for (int m = 0; m < 2; ++m)
            #pragma unroll
            for (int r = 0; r < 4; ++r) f[m][r] = acc[m][n][r];
        float mx = -1e30f;
        #pragma unroll
        for (int r = 0; r < 4; ++r) mx = fmaxf(mx, fmaxf(f[0][r], f[1][r]));
        mx = fmaxf(mx, __shfl_xor(mx, 16));
        mx = fmaxf(mx, __shfl_xor(mx, 32));
        float s = 0.f;
        #pragma unroll
        for (int r = 0; r < 4; ++r) {
            f[0][r] = __expf(f[0][r] - mx); s += f[0][r];
            f[1][r] = __expf(f[1][r] - mx); s += f[1][r];
        }
        s += __shfl_xor(s, 16); s += __shfl_xor(s, 32);
        float inv = 1.f / s;
        int cl = n * 16 + lr;
        #pragma unroll
        for (int m = 0; m < 2; ++m) {
            int d = w * 32 + m * 16 + grp * 4;
            uint2 pk;
            pk.x = (uint)f2bf(f[m][0] * inv) | ((uint)f2bf(f[m][1] * inv) << 16);
            pk.y = (uint)f2bf(f[m][2] * inv) | ((uint)f2bf(f[m][3] * inv) << 16);
            uint off = (uint)(cl * 512 + d * 2) ^ (uint)((cl & 7) << 4);
            *(uint2*)((char*)BQ + off) = pk;
        }
    }
    __syncthreads();   // all waves' q visible

    // ---- GEMM2: out = M @ q ----
    f32x4 acc2[2][4] = {};
    const ushort* Mb = M + (size_t)b * 256 * 256;
    for (int k0 = 0; k0 < 256; k0 += 32) {
        bf16x8 af[2], bq[4];
        #pragma unroll
        for (int m = 0; m < 2; ++m)
            af[m] = *(const bf16x8*)(Mb + (size_t)(w * 32 + m * 16 + lr) * 256 + k0 + grp * 8);
        #pragma unroll
        for (int n = 0; n < 4; ++n) {
            int row = n * 16 + lr;
            uint off = (uint)(row * 512 + (k0 + grp * 8) * 2) ^ (uint)((row & 7) << 4);
            bq[n] = *(const bf16x8*)((const char*)BQ + off);
        }
        #pragma unroll
        for (int m = 0; m < 2; ++m)
            #pragma unroll
            for (int n = 0; n < 4; ++n)
                acc2[m][n] = __builtin_amdgcn_mfma_f32_16x16x32_bf16(af[m], bq[n], acc2[m][n], 0, 0, 0);
    }

    // ---- epilogue: +b_out, column sum-of-squares over 256 rows ----
    __syncthreads();   // ss2 about to be rewritten
    #pragma unroll
    for (int n = 0; n < 4; ++n) {
        float local = 0.f;
        #pragma unroll
        for (int m = 0; m < 2; ++m) {
            int obase = w * 32 + m * 16 + grp * 4;
            #pragma unroll
            for (int r = 0; r < 4; ++r) {
                float f = acc2[m][n][r] + b_out[obase + r];
                acc2[m][n][r] = f;
                local += f * f;
            }
        }
        local += __shfl_xor(local, 16);
        local += __shfl_xor(local, 32);
        if (grp == 0) ss2[w][n * 16 + lr] = local;
    }
    __syncthreads();
    float* ob = out + (size_t)b * C_ * N_;
    #pragma unroll
    for (int n = 0; n < 4; ++n) {
        int cl = n * 16 + lr;
        int cg = col0 + cl;
        float tot = ss2[0][cl] + ss2[1][cl] + ss2[2][cl] + ss2[3][cl]
                  + ss2[4][cl] + ss2[5][cl] + ss2[6][cl] + ss2[7][cl];
        float rs = 16.f / fmaxf(sqrtf(tot), EPS_);
        #pragma unroll
        for (int m = 0; m < 2; ++m) {
            int obase = w * 32 + m * 16 + grp * 4;
            #pragma unroll
            for (int r = 0; r < 4; ++r) {
                int o = obase + r;
                ob[(size_t)o * N_ + cg] = acc2[m][n][r] * rs * g2[o] + xb2[(size_t)o * N_ + cg];
            }
        }
    }
}

extern "C" void kernel_launch(void* const* d_in, const int* in_sizes, int n_in,
                              void* d_out, int out_size, void* d_ws, size_t ws_size,
                              hipStream_t stream) {
    const float* x     = (const float*)d_in[0];
    const float* g1    = (const float*)d_in[1];
    const float* w_qkv = (const float*)d_in[2];
    const float* w_out = (const float*)d_in[3];
    const float* b_out = (const float*)d_in[4];
    const float* g2    = (const float*)d_in[5];
    float* out = (float*)d_out;
    char* ws = (char*)d_ws;

    ushort* Wp     = (ushort*)(ws + 0);          //    393216 B
    float*  ctxp   = (float*)(ws + 393216);      //  16777216 B (32 slices)
    float*  sums_p = (float*)(ws + 17170432);    //    524288 B
    ushort* Mm     = (ushort*)(ws + 17694720);   //   2097152 B (total ~19.8 MB)

    // allow >64KB dynamic LDS for k_kvctx (gfx950 has 160KB/CU)
    hipFuncSetAttribute((const void*)k_kvctx,
                        hipFuncAttributeMaxDynamicSharedMemorySize, 154112);

    k_prep<<<768, 256, 0, stream>>>(w_qkv, g1, Wp);
    k_kvctx<<<dim3(32, 16), 512, 154112, stream>>>(Wp, x, ctxp, sums_p);
    k_fold<<<128, 256, 0, stream>>>(w_out, ctxp, sums_p, Mm);
    k_qfinal<<<dim3(64, 16), 512, 0, stream>>>(Wp, Mm, b_out, g2, x, out);
}

// Round 12
// 133.845 us; speedup vs baseline: 1.7448x; 1.0028x over previous
//
#include <hip/hip_runtime.h>
#include <math.h>

// LinearAttention: B=16, C=256, H=W=64 (N=4096), 8 heads x 32 dim.
// R1: k_fold -> block-per-(b,h) LDS kernel.
// R2: ctx via MFMA; R6: k_qfinal fuses q-GEMM + softmax + M@q + epilogue.
// R10: k_kvctx fuses kv-GEMM + exp + ctx partial (kv round-trip deleted).
// R11: xnbT/k_xconv deleted; rnorm recomputed in-kernel prologues.
// R12: k_qfinal epilogue was writing 4x64B scattered segments (2.35 TB/s
//      effective, 37% of achievable). Now stages scaled result through a
//      128x68 f32 LDS buffer (overlays dead BQ) and streams out + residual
//      with lane=column float4 mapping: 256B/row, 1KB/wave-instr.

#define B_ 16
#define C_ 256
#define N_ 4096
#define SCALE_ 0.17677669529663687f
#define EPS_ 1e-12f

typedef __attribute__((ext_vector_type(8))) short bf16x8;
typedef __attribute__((ext_vector_type(4))) float f32x4;

__device__ __forceinline__ ushort f2bf(float f) {
    union { float f; uint u; } x; x.f = f;
    uint r = (x.u + 0x7FFFu + ((x.u >> 16) & 1u)) >> 16;
    return (ushort)r;
}
__device__ __forceinline__ float bf2f(ushort s) {
    union { uint u; float f; } x; x.u = ((uint)s) << 16;
    return x.f;
}

// ---------------- K1: W' = w_qkv * g1 -> bf16 ----------------
__global__ __launch_bounds__(256) void k_prep(const float* __restrict__ w_qkv,
                                              const float* __restrict__ g1,
                                              ushort* __restrict__ Wp) {
    int o = blockIdx.x, c = threadIdx.x;
    Wp[(size_t)o * 256 + c] = f2bf(w_qkv[(size_t)o * 256 + c] * g1[c]);
}

// ---------------- K2: fused rnorm + kv-GEMM + exp + ctx partial -----------
__global__ __launch_bounds__(512) void k_kvctx(const ushort* __restrict__ Wp,
                                               const float* __restrict__ x,
                                               float* __restrict__ ctxp,
                                               float* __restrict__ sums_p) {
    extern __shared__ char lds[];
    ushort (*Asub)[40] = (ushort(*)[40])lds;          // 20480 B
    char* BQ = lds + 20480;                           // 65536 B
    char* P  = lds + 86016;                           // 65536 B
    float* sspA  = (float*)(lds + 151552);            //  2048 B
    float* rinvA = (float*)(lds + 153600);            //   512 B
    const int b = blockIdx.y, s = blockIdx.x;
    const int col0 = s * 128;
    const int t = threadIdx.x, l = t & 63, w = t >> 6;
    const int lr = l & 15, grp = l >> 4;
    const int wn = w & 3, wo = w >> 2;
    const float* xb = x + (size_t)b * C_ * N_ + col0;

    {   // prologue A: per-column sumsq (coalesced: lane = column)
        int col = t & 127, rg = t >> 7;
        float ss = 0.f;
        #pragma unroll 8
        for (int i = 0; i < 64; ++i) {
            float v = xb[(size_t)(rg * 64 + i) * N_ + col];
            ss += v * v;
        }
        sspA[rg * 128 + col] = ss;
    }
    __syncthreads();
    if (t < 128)
        rinvA[t] = 16.f / fmaxf(sqrtf(sspA[t] + sspA[128 + t] + sspA[256 + t] + sspA[384 + t]), EPS_);
    __syncthreads();
    {   // prologue B: xn = bf16(x*rinv) -> BQ[col][c], swz byte ^= (col&7)<<4
        int col = t & 127, rg = t >> 7;
        float rv = rinvA[col];
        uint sw = (uint)((col & 7) << 4);
        #pragma unroll
        for (int i = 0; i < 16; ++i) {
            int c = rg * 64 + i * 4;
            uint2 pk;
            pk.x = (uint)f2bf(xb[(size_t)c * N_ + col] * rv)
                 | ((uint)f2bf(xb[(size_t)(c + 1) * N_ + col] * rv) << 16);
            pk.y = (uint)f2bf(xb[(size_t)(c + 2) * N_ + col] * rv)
                 | ((uint)f2bf(xb[(size_t)(c + 3) * N_ + col] * rv) << 16);
            *(uint2*)(BQ + (((uint)(col * 512 + c * 2)) ^ sw)) = pk;
        }
    }

    #pragma unroll
    for (int p = 0; p < 2; ++p) {
        f32x4 acc[2][8] = {};
        for (int k0 = 0; k0 < 256; k0 += 32) {
            {   // stage Wkv o-rows (p=0: Wp 256.., p=1: Wp 512..)
                int r = t >> 1, ko = (t & 1) * 16;
                const uint4* sa = (const uint4*)(Wp + (size_t)(256 + p * 256 + r) * 256 + k0 + ko);
                *(uint4*)&Asub[r][ko]     = sa[0];
                *(uint4*)&Asub[r][ko + 8] = sa[1];
            }
            __syncthreads();   // first iter also fences prologue BQ writes
            bf16x8 ax[2], bw[8];
            #pragma unroll
            for (int m = 0; m < 2; ++m) {
                int row = wn * 32 + m * 16 + lr;
                uint off = (uint)(row * 512 + (k0 + grp * 8) * 2) ^ (uint)((row & 7) << 4);
                ax[m] = *(const bf16x8*)(BQ + off);
            }
            #pragma unroll
            for (int nf = 0; nf < 8; ++nf)
                bw[nf] = *(const bf16x8*)&Asub[wo * 128 + nf * 16 + lr][grp * 8];
            #pragma unroll
            for (int m = 0; m < 2; ++m)
                #pragma unroll
                for (int nf = 0; nf < 8; ++nf)
                    acc[m][nf] = __builtin_amdgcn_mfma_f32_16x16x32_bf16(ax[m], bw[nf], acc[m][nf], 0, 0, 0);
            __syncthreads();
        }
        if (p == 0) {
            // P[d][n] = bf16(exp(logit)), rows 256B, byte ^= (d&7)<<4
            #pragma unroll
            for (int nf = 0; nf < 8; ++nf) {
                int d = wo * 128 + nf * 16 + lr;
                uint sw = (uint)((d & 7) << 4);
                #pragma unroll
                for (int m = 0; m < 2; ++m) {
                    int n0 = wn * 32 + m * 16 + grp * 4;
                    uint2 pk;
                    pk.x = (uint)f2bf(__expf(acc[m][nf][0])) | ((uint)f2bf(__expf(acc[m][nf][1])) << 16);
                    pk.y = (uint)f2bf(__expf(acc[m][nf][2])) | ((uint)f2bf(__expf(acc[m][nf][3])) << 16);
                    *(uint2*)(P + (((uint)(d * 256 + n0 * 2)) ^ sw)) = pk;
                }
            }
        } else {
            // V[e][n] overlaid onto BQ (xn dead after pass-1 trailing barrier)
            #pragma unroll
            for (int nf = 0; nf < 8; ++nf) {
                int e = wo * 128 + nf * 16 + lr;
                uint sw = (uint)((e & 7) << 4);
                #pragma unroll
                for (int m = 0; m < 2; ++m) {
                    int n0 = wn * 32 + m * 16 + grp * 4;
                    uint2 pk;
                    pk.x = (uint)f2bf(acc[m][nf][0]) | ((uint)f2bf(acc[m][nf][1]) << 16);
                    pk.y = (uint)f2bf(acc[m][nf][2]) | ((uint)f2bf(acc[m][nf][3]) << 16);
                    *(uint2*)(BQ + (((uint)(e * 256 + n0 * 2)) ^ sw)) = pk;
                }
            }
        }
    }
    __syncthreads();   // P and V fully visible

    // per-head ctx: wave = head
    const int h = w;
    f32x4 c3[2][2] = {};
    f32x4 cS[2] = {};
    bf16x8 ones;
    #pragma unroll
    for (int j = 0; j < 8; ++j) ones[j] = (short)0x3F80;   // bf16 1.0
    #pragma unroll
    for (int ks = 0; ks < 4; ++ks) {
        int n0 = ks * 32 + grp * 8;
        bf16x8 pA[2], vB[2];
        #pragma unroll
        for (int df = 0; df < 2; ++df) {
            int d = h * 32 + df * 16 + lr;
            pA[df] = *(const bf16x8*)(P + (((uint)(d * 256 + n0 * 2)) ^ ((uint)((d & 7) << 4))));
        }
        #pragma unroll
        for (int ef = 0; ef < 2; ++ef) {
            int e = h * 32 + ef * 16 + lr;
            vB[ef] = *(const bf16x8*)(BQ + (((uint)(e * 256 + n0 * 2)) ^ ((uint)((e & 7) << 4))));
        }
        #pragma unroll
        for (int df = 0; df < 2; ++df) {
            #pragma unroll
            for (int ef = 0; ef < 2; ++ef)
                c3[df][ef] = __builtin_amdgcn_mfma_f32_16x16x32_bf16(pA[df], vB[ef], c3[df][ef], 0, 0, 0);
            cS[df] = __builtin_amdgcn_mfma_f32_16x16x32_bf16(pA[df], ones, cS[df], 0, 0, 0);
        }
    }
    int bh = b * 8 + h;
    size_t base = ((size_t)s * 128 + bh) * 32;
    #pragma unroll
    for (int df = 0; df < 2; ++df) {
        #pragma unroll
        for (int ef = 0; ef < 2; ++ef)
            #pragma unroll
            for (int r = 0; r < 4; ++r)
                ctxp[(base + df * 16 + grp * 4 + r) * 32 + ef * 16 + lr] = c3[df][ef][r];
        if (lr == 0)
            #pragma unroll
            for (int r = 0; r < 4; ++r)
                sums_p[base + df * 16 + grp * 4 + r] = cS[df][r];
    }
}

// ---------------- K3: M[b][o][h*32+d] = SCALE/stot[d] * sum_e w_out.ctx ----
__global__ __launch_bounds__(256) void k_fold(const float* __restrict__ w_out,
                                              const float* __restrict__ ctxp,
                                              const float* __restrict__ sums_p,
                                              ushort* __restrict__ M) {
    __shared__ float cn[32][33];
    __shared__ float sinv[32];
    int bh = blockIdx.x;
    int b = bh >> 3, h = bh & 7;
    int t = threadIdx.x;
    if (t < 32) {
        float st = 0.f;
        #pragma unroll 8
        for (int s = 0; s < 32; ++s) st += sums_p[(size_t)(s * 128 + bh) * 32 + t];
        sinv[t] = SCALE_ / st;
    }
    #pragma unroll
    for (int i = t; i < 1024; i += 256) {
        int d = i >> 5, e = i & 31;
        float cv = 0.f;
        #pragma unroll 8
        for (int s = 0; s < 32; ++s)
            cv += ctxp[((size_t)(s * 128 + bh) * 32 + d) * 32 + e];
        cn[e][d] = cv;
    }
    __syncthreads();
    float wreg[32];
    const float* wr = w_out + (size_t)t * 256 + h * 32;
    #pragma unroll
    for (int e = 0; e < 32; e += 4) {
        float4 wv = *(const float4*)&wr[e];
        wreg[e] = wv.x; wreg[e + 1] = wv.y; wreg[e + 2] = wv.z; wreg[e + 3] = wv.w;
    }
    float acc[32] = {};
    #pragma unroll
    for (int e = 0; e < 32; ++e) {
        float we = wreg[e];
        #pragma unroll
        for (int d = 0; d < 32; ++d) acc[d] += we * cn[e][d];
    }
    ushort* Mrow = M + ((size_t)b * 256 + t) * 256 + h * 32;
    #pragma unroll
    for (int d = 0; d < 32; ++d) Mrow[d] = f2bf(acc[d] * sinv[d]);
}

// ---------------- K4: fused rnorm + q-GEMM + softmax + M@q + epilogue -----
// grid (64 coltiles, 16 b), 512 threads = 8 waves; wave = head = 32 rows.
// prologue: x -> rinv -> xn=bf16(x*rinv) into swizzled BQ. GEMM1 -> softmax
// -> q overlays BQ -> GEMM2 -> scale -> LDS restage (overlays BQ) ->
// lane=column float4 stream-out of (scaled + x residual).
__global__ __launch_bounds__(512) void k_qfinal(const ushort* __restrict__ Wp,
                                                const ushort* __restrict__ M,
                                                const float* __restrict__ b_out,
                                                const float* __restrict__ g2,
                                                const float* __restrict__ x,
                                                float* __restrict__ out) {
    __shared__ __align__(16) char shmem[34816];  // BQ (32768B) then OUT overlay
    __shared__ float ss2[8][64];
    __shared__ float rinvq[64];
    ushort* BQ = (ushort*)shmem;    // swizzled: byte = (row*512+k*2) ^ ((row&7)<<4)
    float*  OUT = (float*)shmem;    // [128][68] f32 chunk buffer
    const int b = blockIdx.y, col0 = blockIdx.x * 64;
    const int t = threadIdx.x, l = t & 63, w = t >> 6;
    const int lr = l & 15, grp = l >> 4;
    const float* xb2 = x + (size_t)b * C_ * N_;

    {   // prologue A: per-column sumsq
        int col = t & 63, rg = t >> 6;
        float ss = 0.f;
        #pragma unroll 8
        for (int i = 0; i < 32; ++i) {
            float v = xb2[(size_t)(rg * 32 + i) * N_ + col0 + col];
            ss += v * v;
        }
        ss2[rg][col] = ss;
    }
    __syncthreads();
    if (t < 64) {
        float st = ss2[0][t] + ss2[1][t] + ss2[2][t] + ss2[3][t]
                 + ss2[4][t] + ss2[5][t] + ss2[6][t] + ss2[7][t];
        rinvq[t] = 16.f / fmaxf(sqrtf(st), EPS_);
    }
    __syncthreads();
    {   // prologue B: xn -> BQ
        int col = t & 63, rg = t >> 6;
        float rv = rinvq[col];
        uint sw = (uint)((col & 7) << 4);
        #pragma unroll
        for (int i = 0; i < 8; ++i) {
            int c = rg * 32 + i * 4;
            uint2 pk;
            pk.x = (uint)f2bf(xb2[(size_t)c * N_ + col0 + col] * rv)
                 | ((uint)f2bf(xb2[(size_t)(c + 1) * N_ + col0 + col] * rv) << 16);
            pk.y = (uint)f2bf(xb2[(size_t)(c + 2) * N_ + col0 + col] * rv)
                 | ((uint)f2bf(xb2[(size_t)(c + 3) * N_ + col0 + col] * rv) << 16);
            *(uint2*)((char*)BQ + (((uint)(col * 512 + c * 2)) ^ sw)) = pk;
        }
    }
    __syncthreads();

    // ---- GEMM1: q = Wq @ xn (wave w -> rows w*32..w*32+31) ----
    f32x4 acc[2][4] = {};
    for (int k0 = 0; k0 < 256; k0 += 32) {
        bf16x8 af[2], bf[4];
        #pragma unroll
        for (int m = 0; m < 2; ++m)
            af[m] = *(const bf16x8*)(Wp + (size_t)(w * 32 + m * 16 + lr) * 256 + k0 + grp * 8);
        #pragma unroll
        for (int n = 0; n < 4; ++n) {
            int row = n * 16 + lr;
            uint off = (uint)(row * 512 + (k0 + grp * 8) * 2) ^ (uint)((row & 7) << 4);
            bf[n] = *(const bf16x8*)((const char*)BQ + off);
        }
        #pragma unroll
        for (int m = 0; m < 2; ++m)
            #pragma unroll
            for (int n = 0; n < 4; ++n)
                acc[m][n] = __builtin_amdgcn_mfma_f32_16x16x32_bf16(af[m], bf[n], acc[m][n], 0, 0, 0);
    }
    __syncthreads();   // all GEMM1 reads of BQ (xn) complete

    // ---- per-head softmax over d (wave = head), overlay q into BQ ----
    #pragma unroll
    for (int n = 0; n < 4; ++n) {
        float f[2][4];
        #pragma unroll
        for (int m = 0; m < 2; ++m)
            #pragma unroll
            for (int r = 0; r < 4; ++r) f[m][r] = acc[m][n][r];
        float mx = -1e30f;
        #pragma unroll
        for (int r = 0; r < 4; ++r) mx = fmaxf(mx, fmaxf(f[0][r], f[1][r]));
        mx = fmaxf(mx, __shfl_xor(mx, 16));
        mx = fmaxf(mx, __shfl_xor(mx, 32));
        float s = 0.f;
        #pragma unroll
        for (int r = 0; r < 4; ++r) {
            f[0][r] = __expf(f[0][r] - mx); s += f[0][r];
            f[1][r] = __expf(f[1][r] - mx); s += f[1][r];
        }
        s += __shfl_xor(s, 16); s += __shfl_xor(s, 32);
        float inv = 1.f / s;
        int cl = n * 16 + lr;
        #pragma unroll
        for (int m = 0; m < 2; ++m) {
            int d = w * 32 + m * 16 + grp * 4;
            uint2 pk;
            pk.x = (uint)f2bf(f[m][0] * inv) | ((uint)f2bf(f[m][1] * inv) << 16);
            pk.y = (uint)f2bf(f[m][2] * inv) | ((uint)f2bf(f[m][3] * inv) << 16);
            uint off = (uint)(cl * 512 + d * 2) ^ (uint)((cl & 7) << 4);
            *(uint2*)((char*)BQ + off) = pk;
        }
    }
    __syncthreads();   // all waves' q visible

    // ---- GEMM2: out = M @ q ----
    f32x4 acc2[2][4] = {};
    const ushort* Mb = M + (size_t)b * 256 * 256;
    for (int k0 = 0; k0 < 256; k0 += 32) {
        bf16x8 af[2], bq[4];
        #pragma unroll
        for (int m = 0; m < 2; ++m)
            af[m] = *(const bf16x8*)(Mb + (size_t)(w * 32 + m * 16 + lr) * 256 + k0 + grp * 8);
        #pragma unroll
        for (int n = 0; n < 4; ++n) {
            int row = n * 16 + lr;
            uint off = (uint)(row * 512 + (k0 + grp * 8) * 2) ^ (uint)((row & 7) << 4);
            bq[n] = *(const bf16x8*)((const char*)BQ + off);
        }
        #pragma unroll
        for (int m = 0; m < 2; ++m)
            #pragma unroll
            for (int n = 0; n < 4; ++n)
                acc2[m][n] = __builtin_amdgcn_mfma_f32_16x16x32_bf16(af[m], bq[n], acc2[m][n], 0, 0, 0);
    }

    // ---- epilogue: +b_out, column ssq, scale; LDS restage; stream out ----
    __syncthreads();   // ss2 about to be rewritten; BQ reads done
    #pragma unroll
    for (int n = 0; n < 4; ++n) {
        float local = 0.f;
        #pragma unroll
        for (int m = 0; m < 2; ++m) {
            int obase = w * 32 + m * 16 + grp * 4;
            #pragma unroll
            for (int r = 0; r < 4; ++r) {
                float f = acc2[m][n][r] + b_out[obase + r];
                acc2[m][n][r] = f;
                local += f * f;
            }
        }
        local += __shfl_xor(local, 16);
        local += __shfl_xor(local, 32);
        if (grp == 0) ss2[w][n * 16 + lr] = local;
    }
    __syncthreads();
    // scale in registers: acc2 = (acc2)*rs*g2[o]
    #pragma unroll
    for (int n = 0; n < 4; ++n) {
        int cl = n * 16 + lr;
        float tot = ss2[0][cl] + ss2[1][cl] + ss2[2][cl] + ss2[3][cl]
                  + ss2[4][cl] + ss2[5][cl] + ss2[6][cl] + ss2[7][cl];
        float rs = 16.f / fmaxf(sqrtf(tot), EPS_);
        #pragma unroll
        for (int m = 0; m < 2; ++m) {
            int obase = w * 32 + m * 16 + grp * 4;
            #pragma unroll
            for (int r = 0; r < 4; ++r)
                acc2[m][n][r] *= rs * g2[obase + r];
        }
    }
    float* ob = out + (size_t)b * C_ * N_;
    const int chunk = w >> 2;
    #pragma unroll
    for (int ch = 0; ch < 2; ++ch) {
        if (chunk == ch) {   // deposit this wave-group's 128 rows
            #pragma unroll
            for (int n = 0; n < 4; ++n) {
                int cl = n * 16 + lr;
                #pragma unroll
                for (int m = 0; m < 2; ++m) {
                    int rbase = (w & 3) * 32 + m * 16 + grp * 4;
                    #pragma unroll
                    for (int r = 0; r < 4; ++r)
                        OUT[(rbase + r) * 68 + cl] = acc2[m][n][r];
                }
            }
        }
        __syncthreads();
        // stream out 128 rows: lane=column float4 (256B contiguous per row)
        #pragma unroll
        for (int i = 0; i < 4; ++i) {
            int rowl = i * 32 + (t >> 4);
            int grow = ch * 128 + rowl;
            float4 v = *(float4*)&OUT[rowl * 68 + (t & 15) * 4];
            float4 xr = *(const float4*)&xb2[(size_t)grow * N_ + col0 + (t & 15) * 4];
            v.x += xr.x; v.y += xr.y; v.z += xr.z; v.w += xr.w;
            *(float4*)&ob[(size_t)grow * N_ + col0 + (t & 15) * 4] = v;
        }
        __syncthreads();
    }
}

extern "C" void kernel_launch(void* const* d_in, const int* in_sizes, int n_in,
                              void* d_out, int out_size, void* d_ws, size_t ws_size,
                              hipStream_t stream) {
    const float* x     = (const float*)d_in[0];
    const float* g1    = (const float*)d_in[1];
    const float* w_qkv = (const float*)d_in[2];
    const float* w_out = (const float*)d_in[3];
    const float* b_out = (const float*)d_in[4];
    const float* g2    = (const float*)d_in[5];
    float* out = (float*)d_out;
    char* ws = (char*)d_ws;

    ushort* Wp     = (ushort*)(ws + 0);          //    393216 B
    float*  ctxp   = (float*)(ws + 393216);      //  16777216 B (32 slices)
    float*  sums_p = (float*)(ws + 17170432);    //    524288 B
    ushort* Mm     = (ushort*)(ws + 17694720);   //   2097152 B (total ~19.8 MB)

    // allow >64KB dynamic LDS for k_kvctx (gfx950 has 160KB/CU)
    hipFuncSetAttribute((const void*)k_kvctx,
                        hipFuncAttributeMaxDynamicSharedMemorySize, 154112);

    k_prep<<<768, 256, 0, stream>>>(w_qkv, g1, Wp);
    k_kvctx<<<dim3(32, 16), 512, 154112, stream>>>(Wp, x, ctxp, sums_p);
    k_fold<<<128, 256, 0, stream>>>(w_out, ctxp, sums_p, Mm);
    k_qfinal<<<dim3(64, 16), 512, 0, stream>>>(Wp, Mm, b_out, g2, x, out);
}